// Round 1
// baseline (1050.964 us; speedup 1.0000x reference)
//
#include <hip/hip_runtime.h>
#include <math.h>

// B=64 N=1025 D=384 K=8 R=8 KS=8 H=128 CIN=1152 OUT=384 ; rank m = 2*K*R = 128
static const int Bb = 64, Nn = 1025, Dd = 384, Kk = 8, Rr = 8, Hh = 128, CINc = 1152, OUTo = 384;

// ---- workspace layout (float offsets); total 39,491,328 floats = 150.7 MiB ----
#define OFF_PSTAT 0u          // 64*8*2*384 = 393216
#define OFF_Z     393216u     // 73728
#define OFF_H     466944u     // 8192
#define OFF_RC    475136u     // 512
#define OFF_RG    475648u     // 64
#define OFF_LG    475712u     // 64
#define OFF_SC    475776u     // 512
#define OFF_SCALE 476288u     // 24576
#define OFF_NP    500864u     // 4608
#define OFF_N2    505472u     // 8 (pad)
#define OFF_P     505600u     // 49152
#define OFF_Q     554752u     // 49152
#define OFF_G     603904u     // 16384
#define OFF_QW    620288u     // 49152
#define OFF_EP    669440u     // 1048576
#define OFF_ZM    1718016u    // 3145728 (X ping-pong buffers alias the front of this)
#define OFF_WB    4863744u    // 9437184
#define OFF_LM    14300928u   // 25190400

__device__ __forceinline__ float gelu_t(float v){
    float u = 0.7978845608028654f*(v + 0.044715f*v*v*v);
    return 0.5f*v*(1.0f + tanhf(u));
}
__device__ __forceinline__ float sigm(float v){ return 1.0f/(1.0f+expf(-v)); }

// ---- per-(b,d) token stats, partial over 8 token slices (deterministic 2-stage) ----
__global__ __launch_bounds__(384) void k_stats(const float* __restrict__ x, float* __restrict__ ps){
    int s = blockIdx.x, b = blockIdx.y, d = threadIdx.x;
    int n0 = s*129, n1 = n0+129 < Nn ? n0+129 : Nn;
    const float* xb = x + (size_t)b*Nn*Dd + d;
    float sm = 0.f, sq = 0.f;
    for (int n = n0; n < n1; ++n){ float v = xb[(size_t)n*Dd]; sm += v; sq += v*v; }
    ps[((size_t)(b*8+s)*2+0)*Dd + d] = sm;
    ps[((size_t)(b*8+s)*2+1)*Dd + d] = sq;
}

__global__ __launch_bounds__(384) void k_statsfin(const float* __restrict__ x, const float* __restrict__ ps, float* __restrict__ z){
    int b = blockIdx.x, d = threadIdx.x;
    float sm = 0.f, sq = 0.f;
    for (int s = 0; s < 8; ++s){
        sm += ps[((size_t)(b*8+s)*2+0)*Dd + d];
        sq += ps[((size_t)(b*8+s)*2+1)*Dd + d];
    }
    float mean = sm*(1.0f/Nn);
    float var  = sq*(1.0f/Nn) - mean*mean;
    z[(size_t)b*CINc + d]        = x[(size_t)b*Nn*Dd + d];  // cls token
    z[(size_t)b*CINc + Dd + d]   = mean;
    z[(size_t)b*CINc + 2*Dd + d] = var;
}

// ---- control MLP: h = gelu(z@W1^T+b1); then rot/gate/scale heads ----
__global__ __launch_bounds__(128) void k_mlp(const float* __restrict__ z, const float* __restrict__ w1, const float* __restrict__ b1,
    const float* __restrict__ w_rot, const float* __restrict__ b_rot,
    const float* __restrict__ w_rg, const float* __restrict__ b_rg,
    const float* __restrict__ w_lg, const float* __restrict__ b_lg,
    const float* __restrict__ w_sc, const float* __restrict__ b_sc,
    float* __restrict__ h, float* __restrict__ rc, float* __restrict__ rg, float* __restrict__ lg, float* __restrict__ sc){
    __shared__ float zs[1152];
    __shared__ float hs[128];
    int b = blockIdx.x, t = threadIdx.x;
    for (int c = t; c < CINc; c += Hh) zs[c] = z[(size_t)b*CINc + c];
    __syncthreads();
    float a = b1[t];
    const float* wrow = w1 + (size_t)t*CINc;
    for (int c = 0; c < CINc; ++c) a += zs[c]*wrow[c];
    float g = gelu_t(a);
    hs[t] = g;
    h[(size_t)b*Hh + t] = g;
    __syncthreads();
    if (t < 8){
        float acc = b_rot[t]; const float* w = w_rot + (size_t)t*Hh;
        for (int c = 0; c < Hh; ++c) acc += hs[c]*w[c];
        rc[b*8+t] = tanhf(acc);
    } else if (t == 8){
        float acc = b_rg[0];
        for (int c = 0; c < Hh; ++c) acc += hs[c]*w_rg[c];
        rg[b] = sigm(acc);
    } else if (t == 9){
        float acc = b_lg[0];
        for (int c = 0; c < Hh; ++c) acc += hs[c]*w_lg[c];
        lg[b] = sigm(acc);
    } else if (t < 18){
        int q = t-10; float acc = b_sc[q]; const float* w = w_sc + (size_t)q*Hh;
        for (int c = 0; c < Hh; ++c) acc += hs[c]*w[c];
        sc[b*8+q] = tanhf(acc);
    }
}

// ---- per-(b,o) output scale: 1 + ss*tanh(sc @ scale_basis) ----
__global__ __launch_bounds__(384) void k_scalevec(const float* __restrict__ sc, const float* __restrict__ sbasis,
                                                  const float* __restrict__ sstr, float* __restrict__ scalev){
    int b = blockIdx.x, o = threadIdx.x;
    float acc = 0.f;
    for (int q = 0; q < 8; ++q) acc += sc[b*8+q]*sbasis[q*OUTo + o];
    scalev[(size_t)b*OUTo + o] = 1.0f + sstr[0]*tanhf(acc);
}

// ---- ||basis_k||_F^2 partials (deterministic tree reduce) ----
__global__ __launch_bounds__(256) void k_normpart(const float* __restrict__ lb, const float* __restrict__ rb, float* __restrict__ np){
    int blk = blockIdx.x, k = blockIdx.y, t = threadIdx.x;
    int idx = blk*256 + t;                 // 576*256 = 147456 = 384*384 exactly
    int d = idx/Dd, e = idx - d*Dd;
    const float* Ld = lb + ((size_t)k*Dd + d)*Rr;
    const float* Re = rb + ((size_t)k*Dd + e)*Rr;
    const float* Rd = rb + ((size_t)k*Dd + d)*Rr;
    const float* Le = lb + ((size_t)k*Dd + e)*Rr;
    float v = 0.f;
    #pragma unroll
    for (int r = 0; r < Rr; ++r) v += Ld[r]*Re[r] - Rd[r]*Le[r];
    __shared__ float red[256];
    red[t] = v*v; __syncthreads();
    for (int sft = 128; sft > 0; sft >>= 1){ if (t < sft) red[t] += red[t+sft]; __syncthreads(); }
    if (t == 0) np[k*576 + blk] = red[0];
}

__global__ __launch_bounds__(64) void k_normfin(const float* __restrict__ np, float* __restrict__ n2){
    int k = blockIdx.x, t = threadIdx.x;
    float s = 0.f;
    for (int i = t; i < 576; i += 64) s += np[k*576 + i];
    for (int m = 32; m > 0; m >>= 1) s += __shfl_xor(s, m, 64);
    if (t == 0) n2[k] = s;
}

// ---- build P=[L|R], Q=[R|L]  (384 x 128, row-major d-major) ----
__global__ __launch_bounds__(256) void k_pq(const float* __restrict__ lb, const float* __restrict__ rb,
                                            float* __restrict__ P, float* __restrict__ Q){
    int idx = blockIdx.x*256 + threadIdx.x;   // < 49152
    int d = idx >> 7, j = idx & 127;
    int k = (j & 63) >> 3, r = j & 7;
    float lv = lb[((size_t)k*Dd + d)*Rr + r];
    float rv = rb[((size_t)k*Dd + d)*Rr + r];
    P[idx] = (j < 64) ? lv : rv;
    Q[idx] = (j < 64) ? rv : lv;
}

// ---- G = Q^T P (128x128) ----
__global__ __launch_bounds__(128) void k_gram(const float* __restrict__ P, const float* __restrict__ Q, float* __restrict__ G){
    int i = blockIdx.x, j = threadIdx.x;
    float acc = 0.f;
    for (int d = 0; d < Dd; ++d) acc += Q[d*128 + i]*P[d*128 + j];
    G[i*128 + j] = acc;
}

// ---- QW = Q^T Wsh^T (128 x 384) ----
__global__ __launch_bounds__(384) void k_qw(const float* __restrict__ Q, const float* __restrict__ Wsh, float* __restrict__ QW){
    int i = blockIdx.x, o = threadIdx.x;
    float acc = 0.f;
    for (int d = 0; d < Dd; ++d) acc += Q[d*128 + i]*Wsh[(size_t)o*Dd + d];
    QW[(size_t)i*OUTo + o] = acc;
}

// ---- one Neumann step: Xout = B0 + DG * Xin  (X col-major per batch: X[(b*128+j)*128+i]) ----
// B0 = D + D G D ; at convergence X = (I-DG)^{-1} D (I+GD), E = D + X.
__global__ __launch_bounds__(256) void k_neumann(const float* __restrict__ G, const float* __restrict__ rc, const float* __restrict__ n2,
                                                 const float* __restrict__ Xin, float* __restrict__ Xout, int init){
    __shared__ float ds[128];
    __shared__ float GsT[128*130];   // GsT[m*130+i] = G[i][m]
    __shared__ float Xs[16*130];     // Xs[jl*130+m] = X[m][j0+jl]
    int jg = blockIdx.x, b = blockIdx.y, t = threadIdx.x;
    int j0 = jg*16;
    if (t < 128){
        int k = (t & 63) >> 3;
        float nrm = fmaxf(sqrtf(n2[k]), 1e-6f);
        float al = 0.5f*rc[b*8+k]/nrm;
        ds[t] = (t < 64) ? al : -al;
    }
    for (int lin = t; lin < 16384; lin += 256){
        int i = lin >> 7, m = lin & 127;
        GsT[m*130 + i] = G[lin];
    }
    __syncthreads();
    for (int u = 0; u < 8; ++u){
        int lin = t + 256*u;          // < 2048
        int jl = lin >> 7, m = lin & 127;
        int j = j0 + jl;
        float v;
        if (init) v = ds[m]*GsT[j*130 + m]*ds[j] + ((m == j) ? ds[m] : 0.f);
        else      v = Xin[((size_t)b*128 + j)*128 + m];
        Xs[jl*130 + m] = v;
    }
    __syncthreads();
    int jl = t >> 4, il = t & 15;
    int j = j0 + jl;
    float dj = ds[j];
    const float* xc = &Xs[jl*130];
    #pragma unroll
    for (int s = 0; s < 8; ++s){
        int i = il + 16*s;
        float acc = 0.f;
        #pragma unroll 4
        for (int m = 0; m < 128; ++m) acc += GsT[m*130 + i]*xc[m];
        float di = ds[i];
        float outv = di*(GsT[j*130 + i]*dj + acc) + ((i == j) ? di : 0.f);
        Xout[((size_t)b*128 + j)*128 + i] = outv;
    }
}

// ---- Ep = rot_gate * (D + X)  (row-major [b][i][j]) ----
__global__ __launch_bounds__(128) void k_ep(const float* __restrict__ X, const float* __restrict__ rc, const float* __restrict__ n2,
                                            const float* __restrict__ rg, float* __restrict__ Ep){
    int i = blockIdx.x, b = blockIdx.y, j = threadIdx.x;
    float v = X[((size_t)b*128 + j)*128 + i];
    if (i == j){
        int k = (i & 63) >> 3;
        float nrm = fmaxf(sqrtf(n2[k]), 1e-6f);
        float al = 0.5f*rc[b*8+k]/nrm;
        v += (i < 64) ? al : -al;
    }
    Ep[((size_t)b*128 + i)*128 + j] = rg[b]*v;
}

// ---- Z = Ep @ QW  (b,128,384) ----
__global__ __launch_bounds__(384) void k_zmat(const float* __restrict__ Ep, const float* __restrict__ QW, float* __restrict__ Z){
    __shared__ float Es[4*128];
    int ig = blockIdx.x, b = blockIdx.y, t = threadIdx.x;
    int i0 = ig*4;
    for (int lin = t; lin < 512; lin += 384)
        Es[lin] = Ep[((size_t)b*128 + i0 + (lin >> 7))*128 + (lin & 127)];
    __syncthreads();
    float a0=0.f, a1=0.f, a2=0.f, a3=0.f;
    for (int m = 0; m < 128; ++m){
        float qw = QW[(size_t)m*OUTo + t];
        a0 += Es[m]*qw; a1 += Es[128+m]*qw; a2 += Es[256+m]*qw; a3 += Es[384+m]*qw;
    }
    size_t base = ((size_t)b*128 + i0)*OUTo + t;
    Z[base] = a0; Z[base+OUTo] = a1; Z[base+2*OUTo] = a2; Z[base+3*OUTo] = a3;
}

// ---- Wb = Wsh^T + P @ Z  (b,384,384) ----
__global__ __launch_bounds__(256) void k_wb(const float* __restrict__ Z, const float* __restrict__ P,
                                            const float* __restrict__ Wsh, float* __restrict__ Wb){
    __shared__ float Zs[128*64];
    int ot = blockIdx.x, b = blockIdx.y, t = threadIdx.x;
    int o0 = ot*64;
    for (int lin = t; lin < 8192; lin += 256){
        int m = lin >> 6, ol = lin & 63;
        Zs[lin] = Z[((size_t)b*128 + m)*OUTo + o0 + ol];
    }
    __syncthreads();
    int ol = t & 63, dg = t >> 6;
    for (int s = 0; s < 96; ++s){
        int d = dg + 4*s;                          // wave-uniform d -> P row broadcast
        float acc = Wsh[(size_t)(o0+ol)*Dd + d];
        const float* Pr = P + (size_t)d*128;
        #pragma unroll 4
        for (int m = 0; m < 128; ++m) acc += Pr[m]*Zs[m*64 + ol];
        Wb[((size_t)b*Dd + d)*OUTo + o0 + ol] = acc;
    }
}

// ---- lm = [cls, patch + local_gate*(dwconv3x3(patch) - patch)] ----
__global__ __launch_bounds__(384) void k_lm(const float* __restrict__ x, const float* __restrict__ kw,
                                            const float* __restrict__ lg, float* __restrict__ lm){
    int n = blockIdx.x, b = blockIdx.y, d = threadIdx.x;
    size_t base = (size_t)b*Nn*Dd + d;
    float xv = x[base + (size_t)n*Dd];
    float outv;
    if (n == 0) outv = xv;
    else {
        int p = n-1, gy = p >> 5, gx = p & 31;
        float acc = 0.f;
        #pragma unroll
        for (int ky = 0; ky < 3; ++ky){
            int yy = gy + ky - 1;
            if ((unsigned)yy < 32u){
                #pragma unroll
                for (int kx = 0; kx < 3; ++kx){
                    int xx = gx + kx - 1;
                    if ((unsigned)xx < 32u){
                        int nn = 1 + (yy << 5) + xx;
                        acc += x[base + (size_t)nn*Dd]*kw[d*9 + ky*3 + kx];
                    }
                }
            }
        }
        float l = lg[b];
        outv = xv + l*(acc - xv);
    }
    lm[base + (size_t)n*Dd] = outv;
}

// ---- out = (lm @ Wb + bias) * scale   (batched 1025x384 @ 384x384, f32 SIMT tile) ----
__global__ __launch_bounds__(256) void k_gemm(const float* __restrict__ lm, const float* __restrict__ Wb,
                                              const float* __restrict__ bias, const float* __restrict__ scalev,
                                              float* __restrict__ out){
    __shared__ float As[16*64];
    __shared__ float Bs[16*64];
    int b = blockIdx.y;
    int nt = blockIdx.x / 6, ot = blockIdx.x % 6;
    int n0 = nt*64, o0 = ot*64;
    int t = threadIdx.x;
    int ty = t >> 4, tx = t & 15;
    float acc[4][4] = {};
    const float* lmb = lm + (size_t)b*Nn*Dd;
    const float* Wbb = Wb + (size_t)b*Dd*OUTo;
    int am = t >> 2, ak = (t & 3)*4;     // A: 64 rows x 16 k
    int bk = t >> 4, bn = (t & 15)*4;    // B: 16 k x 64 o
    for (int kt = 0; kt < 24; ++kt){
        int k0 = kt*16;
        int row = n0 + am;
        float4 av;
        if (row < Nn) av = *(const float4*)(lmb + (size_t)row*Dd + k0 + ak);
        else av = make_float4(0.f,0.f,0.f,0.f);
        As[(ak+0)*64+am]=av.x; As[(ak+1)*64+am]=av.y; As[(ak+2)*64+am]=av.z; As[(ak+3)*64+am]=av.w;
        *(float4*)(&Bs[bk*64 + bn]) = *(const float4*)(Wbb + (size_t)(k0+bk)*OUTo + o0 + bn);
        __syncthreads();
        #pragma unroll
        for (int kk = 0; kk < 16; ++kk){
            float4 a  = *(const float4*)(&As[kk*64 + ty*4]);
            float4 bq = *(const float4*)(&Bs[kk*64 + tx*4]);
            acc[0][0]+=a.x*bq.x; acc[0][1]+=a.x*bq.y; acc[0][2]+=a.x*bq.z; acc[0][3]+=a.x*bq.w;
            acc[1][0]+=a.y*bq.x; acc[1][1]+=a.y*bq.y; acc[1][2]+=a.y*bq.z; acc[1][3]+=a.y*bq.w;
            acc[2][0]+=a.z*bq.x; acc[2][1]+=a.z*bq.y; acc[2][2]+=a.z*bq.z; acc[2][3]+=a.z*bq.w;
            acc[3][0]+=a.w*bq.x; acc[3][1]+=a.w*bq.y; acc[3][2]+=a.w*bq.z; acc[3][3]+=a.w*bq.w;
        }
        __syncthreads();
    }
    const float* sv = scalev + (size_t)b*OUTo;
    int oc = o0 + tx*4;
    #pragma unroll
    for (int i2 = 0; i2 < 4; ++i2){
        int row = n0 + ty*4 + i2;
        if (row < Nn){
            float4 o4;
            o4.x = sv[oc+0]*(bias[oc+0] + acc[i2][0]);
            o4.y = sv[oc+1]*(bias[oc+1] + acc[i2][1]);
            o4.z = sv[oc+2]*(bias[oc+2] + acc[i2][2]);
            o4.w = sv[oc+3]*(bias[oc+3] + acc[i2][3]);
            *(float4*)(out + ((size_t)b*Nn + row)*OUTo + oc) = o4;
        }
    }
}

extern "C" void kernel_launch(void* const* d_in, const int* in_sizes, int n_in,
                              void* d_out, int out_size, void* d_ws, size_t ws_size,
                              hipStream_t stream){
    const float* x     = (const float*)d_in[0];
    const float* Wsh   = (const float*)d_in[1];
    const float* bias  = (const float*)d_in[2];
    const float* lb    = (const float*)d_in[3];
    const float* rb    = (const float*)d_in[4];
    const float* sbasis= (const float*)d_in[5];
    const float* sstr  = (const float*)d_in[6];
    const float* kw    = (const float*)d_in[7];
    const float* w1    = (const float*)d_in[8];
    const float* b1    = (const float*)d_in[9];
    const float* w_rot = (const float*)d_in[10];
    const float* b_rot = (const float*)d_in[11];
    const float* w_rg  = (const float*)d_in[12];
    const float* b_rg  = (const float*)d_in[13];
    const float* w_lg  = (const float*)d_in[14];
    const float* b_lg  = (const float*)d_in[15];
    const float* w_sc  = (const float*)d_in[16];
    const float* b_sc  = (const float*)d_in[17];
    float* out = (float*)d_out;
    float* ws  = (float*)d_ws;

    float* ps     = ws + OFF_PSTAT;
    float* z      = ws + OFF_Z;
    float* h      = ws + OFF_H;
    float* rc     = ws + OFF_RC;
    float* rg     = ws + OFF_RG;
    float* lg     = ws + OFF_LG;
    float* sc     = ws + OFF_SC;
    float* scalev = ws + OFF_SCALE;
    float* np     = ws + OFF_NP;
    float* n2     = ws + OFF_N2;
    float* P      = ws + OFF_P;
    float* Q      = ws + OFF_Q;
    float* G      = ws + OFF_G;
    float* QW     = ws + OFF_QW;
    float* Ep     = ws + OFF_EP;
    float* Zm     = ws + OFF_ZM;
    float* Wb     = ws + OFF_WB;
    float* lmb    = ws + OFF_LM;
    float* Xa     = ws + OFF_ZM;            // aliases Zm; X dead before Zm written
    float* Xb     = ws + OFF_ZM + 1048576u;

    k_stats   <<<dim3(8, Bb), 384, 0, stream>>>(x, ps);
    k_statsfin<<<Bb, 384, 0, stream>>>(x, ps, z);
    k_mlp     <<<Bb, 128, 0, stream>>>(z, w1, b1, w_rot, b_rot, w_rg, b_rg, w_lg, b_lg, w_sc, b_sc,
                                       h, rc, rg, lg, sc);
    k_scalevec<<<Bb, 384, 0, stream>>>(sc, sbasis, sstr, scalev);
    k_normpart<<<dim3(576, Kk), 256, 0, stream>>>(lb, rb, np);
    k_normfin <<<Kk, 64, 0, stream>>>(np, n2);
    k_pq      <<<192, 256, 0, stream>>>(lb, rb, P, Q);
    k_gram    <<<128, 128, 0, stream>>>(P, Q, G);
    k_qw      <<<128, 384, 0, stream>>>(Q, Wsh, QW);
    k_neumann <<<dim3(8, Bb), 256, 0, stream>>>(G, rc, n2, Xa, Xb, 1);
    k_neumann <<<dim3(8, Bb), 256, 0, stream>>>(G, rc, n2, Xb, Xa, 0);
    k_neumann <<<dim3(8, Bb), 256, 0, stream>>>(G, rc, n2, Xa, Xb, 0);
    k_neumann <<<dim3(8, Bb), 256, 0, stream>>>(G, rc, n2, Xb, Xa, 0);
    k_ep      <<<dim3(128, Bb), 128, 0, stream>>>(Xa, rc, n2, rg, Ep);
    k_zmat    <<<dim3(32, Bb), 384, 0, stream>>>(Ep, QW, Zm);
    k_wb      <<<dim3(6, Bb), 256, 0, stream>>>(Zm, P, Wsh, Wb);
    k_lm      <<<dim3(Nn, Bb), 384, 0, stream>>>(x, kw, lg, lmb);
    k_gemm    <<<dim3(102, Bb), 256, 0, stream>>>(lmb, Wb, bias, scalev, out);
}

// Round 2
// 575.716 us; speedup vs baseline: 1.8255x; 1.8255x over previous
//
#include <hip/hip_runtime.h>
#include <hip/hip_bf16.h>
#include <math.h>

// B=64 N=1025 D=384 K=8 R=8 KS=8 H=128 CIN=1152 OUT=384 ; rank m = 2*K*R = 128
static const int Bb = 64, Nn = 1025, Dd = 384, Kk = 8, Rr = 8, Hh = 128, CINc = 1152, OUTo = 384;

// ---- workspace layout (float offsets); total 22,726,400 floats = 90.9 MiB ----
#define OFF_PSTAT 0u          // 393216
#define OFF_Z     393216u     // 73728
#define OFF_H     466944u     // 8192
#define OFF_RC    475136u     // 512
#define OFF_RG    475648u     // 64
#define OFF_LG    475712u     // 64
#define OFF_SC    475776u     // 512
#define OFF_SCALE 476288u     // 24576
#define OFF_NP    500864u     // 4608
#define OFF_N2    505472u     // 128
#define OFF_P     505600u     // 49152 (f32)
#define OFF_Q     554752u     // 49152 (f32)
#define OFF_G     603904u     // 16384
#define OFF_QW    620288u     // 49152 (f32)
#define OFF_PB    669440u     // 24576  (bf16 384x128)
#define OFF_EP    694016u     // 1048576
#define OFF_XA    1742592u    // 1048576
#define OFF_XB    2791168u    // 1048576
#define OFF_ZT    3839744u    // 1572864 (bf16 64x384x128)
#define OFF_WBT   5412608u    // 4718592 (bf16 64x384x384)
#define OFF_LM    10131200u   // 12595200 (bf16 64x1025x384)

typedef __attribute__((ext_vector_type(8))) short short8;
typedef __attribute__((ext_vector_type(8))) __bf16 bf16x8;
typedef __attribute__((ext_vector_type(4))) float f32x4;

#define MFMA_BF16(a,b,c) __builtin_amdgcn_mfma_f32_16x16x32_bf16( \
    __builtin_bit_cast(bf16x8,(a)), __builtin_bit_cast(bf16x8,(b)), (c), 0, 0, 0)

__device__ __forceinline__ float gelu_t(float v){
    float u = 0.7978845608028654f*(v + 0.044715f*v*v*v);
    return 0.5f*v*(1.0f + tanhf(u));
}
__device__ __forceinline__ float sigm(float v){ return 1.0f/(1.0f+expf(-v)); }
__device__ __forceinline__ unsigned short f2bf(float v){
    return __builtin_bit_cast(unsigned short, __float2bfloat16(v));
}

// ---- per-(b,d) token stats, partial over 8 token slices ----
__global__ __launch_bounds__(384) void k_stats(const float* __restrict__ x, float* __restrict__ ps){
    int s = blockIdx.x, b = blockIdx.y, d = threadIdx.x;
    int n0 = s*129, n1 = n0+129 < Nn ? n0+129 : Nn;
    const float* xb = x + (size_t)b*Nn*Dd + d;
    float sm = 0.f, sq = 0.f;
    for (int n = n0; n < n1; ++n){ float v = xb[(size_t)n*Dd]; sm += v; sq += v*v; }
    ps[((size_t)(b*8+s)*2+0)*Dd + d] = sm;
    ps[((size_t)(b*8+s)*2+1)*Dd + d] = sq;
}

__global__ __launch_bounds__(384) void k_statsfin(const float* __restrict__ x, const float* __restrict__ ps, float* __restrict__ z){
    int b = blockIdx.x, d = threadIdx.x;
    float sm = 0.f, sq = 0.f;
    for (int s = 0; s < 8; ++s){
        sm += ps[((size_t)(b*8+s)*2+0)*Dd + d];
        sq += ps[((size_t)(b*8+s)*2+1)*Dd + d];
    }
    float mean = sm*(1.0f/Nn);
    float var  = sq*(1.0f/Nn) - mean*mean;
    z[(size_t)b*CINc + d]        = x[(size_t)b*Nn*Dd + d];
    z[(size_t)b*CINc + Dd + d]   = mean;
    z[(size_t)b*CINc + 2*Dd + d] = var;
}

// ---- control MLP ----
__global__ __launch_bounds__(128) void k_mlp(const float* __restrict__ z, const float* __restrict__ w1, const float* __restrict__ b1,
    const float* __restrict__ w_rot, const float* __restrict__ b_rot,
    const float* __restrict__ w_rg, const float* __restrict__ b_rg,
    const float* __restrict__ w_lg, const float* __restrict__ b_lg,
    const float* __restrict__ w_sc, const float* __restrict__ b_sc,
    float* __restrict__ h, float* __restrict__ rc, float* __restrict__ rg, float* __restrict__ lg, float* __restrict__ sc){
    __shared__ float zs[1152];
    __shared__ float hs[128];
    int b = blockIdx.x, t = threadIdx.x;
    for (int c = t; c < CINc; c += Hh) zs[c] = z[(size_t)b*CINc + c];
    __syncthreads();
    float a = b1[t];
    const float* wrow = w1 + (size_t)t*CINc;
    for (int c = 0; c < CINc; ++c) a += zs[c]*wrow[c];
    float g = gelu_t(a);
    hs[t] = g;
    h[(size_t)b*Hh + t] = g;
    __syncthreads();
    if (t < 8){
        float acc = b_rot[t]; const float* w = w_rot + (size_t)t*Hh;
        for (int c = 0; c < Hh; ++c) acc += hs[c]*w[c];
        rc[b*8+t] = tanhf(acc);
    } else if (t == 8){
        float acc = b_rg[0];
        for (int c = 0; c < Hh; ++c) acc += hs[c]*w_rg[c];
        rg[b] = sigm(acc);
    } else if (t == 9){
        float acc = b_lg[0];
        for (int c = 0; c < Hh; ++c) acc += hs[c]*w_lg[c];
        lg[b] = sigm(acc);
    } else if (t < 18){
        int q = t-10; float acc = b_sc[q]; const float* w = w_sc + (size_t)q*Hh;
        for (int c = 0; c < Hh; ++c) acc += hs[c]*w[c];
        sc[b*8+q] = tanhf(acc);
    }
}

__global__ __launch_bounds__(384) void k_scalevec(const float* __restrict__ sc, const float* __restrict__ sbasis,
                                                  const float* __restrict__ sstr, float* __restrict__ scalev){
    int b = blockIdx.x, o = threadIdx.x;
    float acc = 0.f;
    for (int q = 0; q < 8; ++q) acc += sc[b*8+q]*sbasis[q*OUTo + o];
    scalev[(size_t)b*OUTo + o] = 1.0f + sstr[0]*tanhf(acc);
}

// ---- ||basis_k||_F^2 partials ----
__global__ __launch_bounds__(256) void k_normpart(const float* __restrict__ lb, const float* __restrict__ rb, float* __restrict__ np){
    int blk = blockIdx.x, k = blockIdx.y, t = threadIdx.x;
    int idx = blk*256 + t;
    int d = idx/Dd, e = idx - d*Dd;
    const float* Ld = lb + ((size_t)k*Dd + d)*Rr;
    const float* Re = rb + ((size_t)k*Dd + e)*Rr;
    const float* Rd = rb + ((size_t)k*Dd + d)*Rr;
    const float* Le = lb + ((size_t)k*Dd + e)*Rr;
    float v = 0.f;
    #pragma unroll
    for (int r = 0; r < Rr; ++r) v += Ld[r]*Re[r] - Rd[r]*Le[r];
    __shared__ float red[256];
    red[t] = v*v; __syncthreads();
    for (int sft = 128; sft > 0; sft >>= 1){ if (t < sft) red[t] += red[t+sft]; __syncthreads(); }
    if (t == 0) np[k*576 + blk] = red[0];
}

__global__ __launch_bounds__(64) void k_normfin(const float* __restrict__ np, float* __restrict__ n2){
    int k = blockIdx.x, t = threadIdx.x;
    float s = 0.f;
    for (int i = t; i < 576; i += 64) s += np[k*576 + i];
    for (int m = 32; m > 0; m >>= 1) s += __shfl_xor(s, m, 64);
    if (t == 0) n2[k] = s;
}

// ---- build P=[L|R] (f32 + bf16), Q=[R|L] ----
__global__ __launch_bounds__(256) void k_pq(const float* __restrict__ lb, const float* __restrict__ rb,
                                            float* __restrict__ P, float* __restrict__ Q, unsigned short* __restrict__ Pb){
    int idx = blockIdx.x*256 + threadIdx.x;   // < 49152
    int d = idx >> 7, j = idx & 127;
    int k = (j & 63) >> 3, r = j & 7;
    float lv = lb[((size_t)k*Dd + d)*Rr + r];
    float rv = rb[((size_t)k*Dd + d)*Rr + r];
    float pv = (j < 64) ? lv : rv;
    P[idx] = pv;
    Pb[idx] = f2bf(pv);
    Q[idx] = (j < 64) ? rv : lv;
}

// ---- G = Q^T P (128x128) ----
__global__ __launch_bounds__(128) void k_gram(const float* __restrict__ P, const float* __restrict__ Q, float* __restrict__ G){
    int i = blockIdx.x, j = threadIdx.x;
    float acc = 0.f;
    for (int d = 0; d < Dd; ++d) acc += Q[d*128 + i]*P[d*128 + j];
    G[i*128 + j] = acc;
}

// ---- QW = Q^T Wsh^T (128 x 384) ----
__global__ __launch_bounds__(384) void k_qw(const float* __restrict__ Q, const float* __restrict__ Wsh, float* __restrict__ QW){
    int i = blockIdx.x, o = threadIdx.x;
    float acc = 0.f;
    for (int d = 0; d < Dd; ++d) acc += Q[d*128 + i]*Wsh[(size_t)o*Dd + d];
    QW[(size_t)i*OUTo + o] = acc;
}

// ---- Neumann iteration for (I-DG)^{-1} D (I+GD) ----
__global__ __launch_bounds__(256) void k_neumann(const float* __restrict__ G, const float* __restrict__ rc, const float* __restrict__ n2,
                                                 const float* __restrict__ Xin, float* __restrict__ Xout, int init){
    __shared__ float ds[128];
    __shared__ float GsT[128*130];
    __shared__ float Xs[16*130];
    int jg = blockIdx.x, b = blockIdx.y, t = threadIdx.x;
    int j0 = jg*16;
    if (t < 128){
        int k = (t & 63) >> 3;
        float nrm = fmaxf(sqrtf(n2[k]), 1e-6f);
        float al = 0.5f*rc[b*8+k]/nrm;
        ds[t] = (t < 64) ? al : -al;
    }
    for (int lin = t; lin < 16384; lin += 256){
        int i = lin >> 7, m = lin & 127;
        GsT[m*130 + i] = G[lin];
    }
    __syncthreads();
    for (int u = 0; u < 8; ++u){
        int lin = t + 256*u;
        int jl = lin >> 7, m = lin & 127;
        int j = j0 + jl;
        float v;
        if (init) v = ds[m]*GsT[j*130 + m]*ds[j] + ((m == j) ? ds[m] : 0.f);
        else      v = Xin[((size_t)b*128 + j)*128 + m];
        Xs[jl*130 + m] = v;
    }
    __syncthreads();
    int jl = t >> 4, il = t & 15;
    int j = j0 + jl;
    float dj = ds[j];
    const float* xc = &Xs[jl*130];
    #pragma unroll
    for (int s = 0; s < 8; ++s){
        int i = il + 16*s;
        float acc = 0.f;
        #pragma unroll 4
        for (int m = 0; m < 128; ++m) acc += GsT[m*130 + i]*xc[m];
        float di = ds[i];
        float outv = di*(GsT[j*130 + i]*dj + acc) + ((i == j) ? di : 0.f);
        Xout[((size_t)b*128 + j)*128 + i] = outv;
    }
}

// ---- Ep = rot_gate * (D + X) ----
__global__ __launch_bounds__(128) void k_ep(const float* __restrict__ X, const float* __restrict__ rc, const float* __restrict__ n2,
                                            const float* __restrict__ rg, float* __restrict__ Ep){
    int i = blockIdx.x, b = blockIdx.y, j = threadIdx.x;
    float v = X[((size_t)b*128 + j)*128 + i];
    if (i == j){
        int k = (i & 63) >> 3;
        float nrm = fmaxf(sqrtf(n2[k]), 1e-6f);
        float al = 0.5f*rc[b*8+k]/nrm;
        v += (i < 64) ? al : -al;
    }
    Ep[((size_t)b*128 + i)*128 + j] = rg[b]*v;
}

// ---- ZT[b][o][m] = (Ep @ QW)^T in bf16 ----
__global__ __launch_bounds__(384) void k_zmatT(const float* __restrict__ Ep, const float* __restrict__ QW, unsigned short* __restrict__ ZT){
    __shared__ float Es[4*128];
    int ig = blockIdx.x, b = blockIdx.y, t = threadIdx.x;
    int i0 = ig*4;
    for (int lin = t; lin < 512; lin += 384)
        Es[lin] = Ep[((size_t)b*128 + i0 + (lin >> 7))*128 + (lin & 127)];
    __syncthreads();
    float a0=0.f, a1=0.f, a2=0.f, a3=0.f;
    for (int m = 0; m < 128; ++m){
        float qw = QW[(size_t)m*OUTo + t];
        a0 += Es[m]*qw; a1 += Es[128+m]*qw; a2 += Es[256+m]*qw; a3 += Es[384+m]*qw;
    }
    ushort4 uv;
    uv.x = f2bf(a0); uv.y = f2bf(a1); uv.z = f2bf(a2); uv.w = f2bf(a3);
    *(ushort4*)(ZT + ((size_t)b*OUTo + t)*128 + i0) = uv;
}

// ---- WbT[b][o][d] = Wsh[o][d] + sum_m ZT[b][o][m]*P[d][m]   (MFMA NT, bf16 out) ----
__global__ __launch_bounds__(256) void k_wbt(const unsigned short* __restrict__ ZT, const unsigned short* __restrict__ Pb,
                                             const float* __restrict__ Wsh, unsigned short* __restrict__ WbT){
    __shared__ short8 As[256];
    __shared__ short8 Bs[256];
    int b = blockIdx.y;
    int mt = blockIdx.x/6, nt2 = blockIdx.x%6;
    int m0 = mt*64, n0 = nt2*64;        // m0: o-rows, n0: d-cols
    int t = threadIdx.x;
    int w = t>>6, l = t&63;
    int wr = w>>1, wc = w&1;
    const unsigned short* Ab = ZT + (size_t)b*OUTo*128;
    int lrow = t>>2, lseg = t&3;
    f32x4 acc[2][2];
    #pragma unroll
    for (int mi=0;mi<2;++mi)
        #pragma unroll
        for (int ni=0;ni<2;++ni)
            #pragma unroll
            for (int q=0;q<4;++q) acc[mi][ni][q] = 0.f;
    for (int kt = 0; kt < 4; ++kt){
        int k0 = kt*32;
        short8 av = *(const short8*)(Ab + (size_t)(m0+lrow)*128 + k0 + lseg*8);
        short8 bv = *(const short8*)(Pb + (size_t)(n0+lrow)*128 + k0 + lseg*8);
        __syncthreads();
        As[lseg*64 + lrow] = av;
        Bs[lseg*64 + lrow] = bv;
        __syncthreads();
        short8 a0 = As[(l>>4)*64 + wr*32 + (l&15)];
        short8 a1 = As[(l>>4)*64 + wr*32 + 16 + (l&15)];
        short8 b0 = Bs[(l>>4)*64 + wc*32 + (l&15)];
        short8 b1 = Bs[(l>>4)*64 + wc*32 + 16 + (l&15)];
        acc[0][0] = MFMA_BF16(a0, b0, acc[0][0]);
        acc[0][1] = MFMA_BF16(a0, b1, acc[0][1]);
        acc[1][0] = MFMA_BF16(a1, b0, acc[1][0]);
        acc[1][1] = MFMA_BF16(a1, b1, acc[1][1]);
    }
    unsigned short* Wo = WbT + (size_t)b*OUTo*Dd;
    #pragma unroll
    for (int mi=0;mi<2;++mi){
        #pragma unroll
        for (int ni=0;ni<2;++ni){
            int col = n0 + wc*32 + ni*16 + (l&15);     // d
            #pragma unroll
            for (int r=0;r<4;++r){
                int row = m0 + wr*32 + mi*16 + (l>>4)*4 + r;  // o
                float v = Wsh[(size_t)row*Dd + col] + acc[mi][ni][r];
                Wo[(size_t)row*Dd + col] = f2bf(v);
            }
        }
    }
}

// ---- lm = [cls, patch + local_gate*(dwconv3x3(patch) - patch)]  (bf16 out) ----
__global__ __launch_bounds__(384) void k_lm(const float* __restrict__ x, const float* __restrict__ kw,
                                            const float* __restrict__ lg, unsigned short* __restrict__ lm){
    int n = blockIdx.x, b = blockIdx.y, d = threadIdx.x;
    size_t base = (size_t)b*Nn*Dd + d;
    float xv = x[base + (size_t)n*Dd];
    float outv;
    if (n == 0) outv = xv;
    else {
        int p = n-1, gy = p >> 5, gx = p & 31;
        float acc = 0.f;
        #pragma unroll
        for (int ky = 0; ky < 3; ++ky){
            int yy = gy + ky - 1;
            if ((unsigned)yy < 32u){
                #pragma unroll
                for (int kx = 0; kx < 3; ++kx){
                    int xx = gx + kx - 1;
                    if ((unsigned)xx < 32u){
                        int nn = 1 + (yy << 5) + xx;
                        acc += x[base + (size_t)nn*Dd]*kw[d*9 + ky*3 + kx];
                    }
                }
            }
        }
        float l = lg[b];
        outv = xv + l*(acc - xv);
    }
    lm[base + (size_t)n*Dd] = f2bf(outv);
}

// ---- out = (lm_bf16 @ Wb + bias)*scale via Bt = WbT  (MFMA NT) ----
__global__ __launch_bounds__(256) void k_gemm_nt(const unsigned short* __restrict__ lm, const unsigned short* __restrict__ WbT,
                                                 const float* __restrict__ bias, const float* __restrict__ scalev,
                                                 float* __restrict__ out){
    __shared__ short8 As[256];
    __shared__ short8 Bs[256];
    int b = blockIdx.y;
    int mt = blockIdx.x/6, ot = blockIdx.x%6;
    int n0 = mt*64, o0 = ot*64;
    int t = threadIdx.x;
    int w = t>>6, l = t&63;
    int wr = w>>1, wc = w&1;
    const unsigned short* Ab = lm + (size_t)b*Nn*Dd;
    const unsigned short* Bt = WbT + (size_t)b*OUTo*Dd;
    int lrow = t>>2, lseg = t&3;
    f32x4 acc[2][2];
    #pragma unroll
    for (int mi=0;mi<2;++mi)
        #pragma unroll
        for (int ni=0;ni<2;++ni)
            #pragma unroll
            for (int q=0;q<4;++q) acc[mi][ni][q] = 0.f;
    for (int kt = 0; kt < 12; ++kt){
        int k0 = kt*32;
        short8 av = {0,0,0,0,0,0,0,0};
        int arow = n0 + lrow;
        if (arow < Nn) av = *(const short8*)(Ab + (size_t)arow*Dd + k0 + lseg*8);
        short8 bv = *(const short8*)(Bt + (size_t)(o0+lrow)*Dd + k0 + lseg*8);
        __syncthreads();
        As[lseg*64 + lrow] = av;
        Bs[lseg*64 + lrow] = bv;
        __syncthreads();
        short8 a0 = As[(l>>4)*64 + wr*32 + (l&15)];
        short8 a1 = As[(l>>4)*64 + wr*32 + 16 + (l&15)];
        short8 b0 = Bs[(l>>4)*64 + wc*32 + (l&15)];
        short8 b1 = Bs[(l>>4)*64 + wc*32 + 16 + (l&15)];
        acc[0][0] = MFMA_BF16(a0, b0, acc[0][0]);
        acc[0][1] = MFMA_BF16(a0, b1, acc[0][1]);
        acc[1][0] = MFMA_BF16(a1, b0, acc[1][0]);
        acc[1][1] = MFMA_BF16(a1, b1, acc[1][1]);
    }
    const float* sv = scalev + (size_t)b*OUTo;
    #pragma unroll
    for (int mi=0;mi<2;++mi){
        #pragma unroll
        for (int ni=0;ni<2;++ni){
            int col = o0 + wc*32 + ni*16 + (l&15);
            float svv = sv[col], bvv = bias[col];
            #pragma unroll
            for (int r=0;r<4;++r){
                int row = n0 + wr*32 + mi*16 + (l>>4)*4 + r;
                if (row < Nn)
                    out[((size_t)b*Nn + row)*OUTo + col] = svv*(bvv + acc[mi][ni][r]);
            }
        }
    }
}

extern "C" void kernel_launch(void* const* d_in, const int* in_sizes, int n_in,
                              void* d_out, int out_size, void* d_ws, size_t ws_size,
                              hipStream_t stream){
    const float* x     = (const float*)d_in[0];
    const float* Wsh   = (const float*)d_in[1];
    const float* bias  = (const float*)d_in[2];
    const float* lb    = (const float*)d_in[3];
    const float* rb    = (const float*)d_in[4];
    const float* sbasis= (const float*)d_in[5];
    const float* sstr  = (const float*)d_in[6];
    const float* kw    = (const float*)d_in[7];
    const float* w1    = (const float*)d_in[8];
    const float* b1    = (const float*)d_in[9];
    const float* w_rot = (const float*)d_in[10];
    const float* b_rot = (const float*)d_in[11];
    const float* w_rg  = (const float*)d_in[12];
    const float* b_rg  = (const float*)d_in[13];
    const float* w_lg  = (const float*)d_in[14];
    const float* b_lg  = (const float*)d_in[15];
    const float* w_sc  = (const float*)d_in[16];
    const float* b_sc  = (const float*)d_in[17];
    float* out = (float*)d_out;
    float* ws  = (float*)d_ws;

    float* ps     = ws + OFF_PSTAT;
    float* z      = ws + OFF_Z;
    float* h      = ws + OFF_H;
    float* rc     = ws + OFF_RC;
    float* rg     = ws + OFF_RG;
    float* lg     = ws + OFF_LG;
    float* sc     = ws + OFF_SC;
    float* scalev = ws + OFF_SCALE;
    float* np     = ws + OFF_NP;
    float* n2     = ws + OFF_N2;
    float* P      = ws + OFF_P;
    float* Q      = ws + OFF_Q;
    float* G      = ws + OFF_G;
    float* QW     = ws + OFF_QW;
    unsigned short* Pb  = (unsigned short*)(ws + OFF_PB);
    float* Ep     = ws + OFF_EP;
    float* Xa     = ws + OFF_XA;
    float* Xb     = ws + OFF_XB;
    unsigned short* ZT  = (unsigned short*)(ws + OFF_ZT);
    unsigned short* WbT = (unsigned short*)(ws + OFF_WBT);
    unsigned short* lmb = (unsigned short*)(ws + OFF_LM);

    k_stats   <<<dim3(8, Bb), 384, 0, stream>>>(x, ps);
    k_statsfin<<<Bb, 384, 0, stream>>>(x, ps, z);
    k_mlp     <<<Bb, 128, 0, stream>>>(z, w1, b1, w_rot, b_rot, w_rg, b_rg, w_lg, b_lg, w_sc, b_sc,
                                       h, rc, rg, lg, sc);
    k_scalevec<<<Bb, 384, 0, stream>>>(sc, sbasis, sstr, scalev);
    k_normpart<<<dim3(576, Kk), 256, 0, stream>>>(lb, rb, np);
    k_normfin <<<Kk, 64, 0, stream>>>(np, n2);
    k_pq      <<<192, 256, 0, stream>>>(lb, rb, P, Q, Pb);
    k_gram    <<<128, 128, 0, stream>>>(P, Q, G);
    k_qw      <<<128, 384, 0, stream>>>(Q, Wsh, QW);
    k_neumann <<<dim3(8, Bb), 256, 0, stream>>>(G, rc, n2, Xa, Xb, 1);
    k_neumann <<<dim3(8, Bb), 256, 0, stream>>>(G, rc, n2, Xb, Xa, 0);
    k_neumann <<<dim3(8, Bb), 256, 0, stream>>>(G, rc, n2, Xa, Xb, 0);
    k_neumann <<<dim3(8, Bb), 256, 0, stream>>>(G, rc, n2, Xb, Xa, 0);
    k_ep      <<<dim3(128, Bb), 128, 0, stream>>>(Xa, rc, n2, rg, Ep);
    k_zmatT   <<<dim3(32, Bb), 384, 0, stream>>>(Ep, QW, ZT);
    k_wbt     <<<dim3(36, Bb), 256, 0, stream>>>(ZT, Pb, Wsh, WbT);
    k_lm      <<<dim3(Nn, Bb), 384, 0, stream>>>(x, kw, lg, lmb);
    k_gemm_nt <<<dim3(102, Bb), 256, 0, stream>>>(lmb, WbT, bias, scalev, out);
}

// Round 3
// 410.603 us; speedup vs baseline: 2.5596x; 1.4021x over previous
//
#include <hip/hip_runtime.h>
#include <hip/hip_bf16.h>
#include <math.h>

// B=64 N=1025 D=384 K=8 R=8 KS=8 H=128 CIN=1152 OUT=384 ; rank m = 2*K*R = 128
static const int Bb = 64, Nn = 1025, Dd = 384, Kk = 8, Rr = 8, Hh = 128, CINc = 1152, OUTo = 384;

// ---- workspace layout (float offsets) ----
#define OFF_PSTAT 0u          // 393216
#define OFF_Z     393216u     // 73728
#define OFF_H     466944u     // 8192
#define OFF_RC    475136u     // 512
#define OFF_RG    475648u     // 64
#define OFF_LG    475712u     // 64
#define OFF_SC    475776u     // 512
#define OFF_SCALE 476288u     // 24576
#define OFF_NP    500864u     // 4608
#define OFF_N2    505472u     // 128
#define OFF_P     505600u     // 49152 (f32)
#define OFF_Q     554752u     // 49152 (f32)
#define OFF_G     603904u     // 16384
#define OFF_QW    620288u     // 49152 (f32)
#define OFF_PB    669440u     // 24576  (bf16 384x128)
#define OFF_EP    694016u     // 1048576
#define OFF_XA    1742592u    // 1048576
#define OFF_XB    2791168u    // 1048576
#define OFF_ZT    3839744u    // 1572864 (bf16 64x384x128)
#define OFF_WBT   5412608u    // 4718592 (bf16 64x384x384)
#define OFF_LM    10131200u   // 12595200 (bf16 64x1025x384)

typedef __attribute__((ext_vector_type(8))) short short8;
typedef __attribute__((ext_vector_type(8))) __bf16 bf16x8;
typedef __attribute__((ext_vector_type(4))) float f32x4;

#define MFMA_BF16(a,b,c) __builtin_amdgcn_mfma_f32_16x16x32_bf16( \
    __builtin_bit_cast(bf16x8,(a)), __builtin_bit_cast(bf16x8,(b)), (c), 0, 0, 0)

__device__ __forceinline__ float gelu_t(float v){
    float u = 0.7978845608028654f*(v + 0.044715f*v*v*v);
    return 0.5f*v*(1.0f + tanhf(u));
}
__device__ __forceinline__ float sigm(float v){ return 1.0f/(1.0f+expf(-v)); }
__device__ __forceinline__ unsigned short f2bf(float v){
    return __builtin_bit_cast(unsigned short, __float2bfloat16(v));
}

// ---- per-(b,d) token stats, float4-vectorized, 8 token slices ----
__global__ __launch_bounds__(384) void k_stats(const float* __restrict__ x, float* __restrict__ ps){
    int s = blockIdx.x, b = blockIdx.y, t = threadIdx.x;
    int dq = t % 96, ng = t / 96;          // 96 float4 columns, 4 row groups
    int n0 = s*129, n1 = n0+129 < Nn ? n0+129 : Nn;
    const float4* xb = (const float4*)(x + (size_t)b*Nn*Dd);
    float4 sm = make_float4(0.f,0.f,0.f,0.f), sq = make_float4(0.f,0.f,0.f,0.f);
    for (int n = n0+ng; n < n1; n += 4){
        float4 v = xb[(size_t)n*96 + dq];
        sm.x += v.x; sm.y += v.y; sm.z += v.z; sm.w += v.w;
        sq.x += v.x*v.x; sq.y += v.y*v.y; sq.z += v.z*v.z; sq.w += v.w*v.w;
    }
    __shared__ float4 smS[384];
    __shared__ float4 sqS[384];
    smS[t] = sm; sqS[t] = sq;
    __syncthreads();
    if (t < 96){
        float4 a0 = smS[t], a1 = smS[t+96], a2 = smS[t+192], a3 = smS[t+288];
        float4 q0 = sqS[t], q1 = sqS[t+96], q2 = sqS[t+192], q3 = sqS[t+288];
        float4 a = make_float4(a0.x+a1.x+a2.x+a3.x, a0.y+a1.y+a2.y+a3.y, a0.z+a1.z+a2.z+a3.z, a0.w+a1.w+a2.w+a3.w);
        float4 q = make_float4(q0.x+q1.x+q2.x+q3.x, q0.y+q1.y+q2.y+q3.y, q0.z+q1.z+q2.z+q3.z, q0.w+q1.w+q2.w+q3.w);
        ((float4*)(ps + ((size_t)(b*8+s)*2+0)*Dd))[t] = a;
        ((float4*)(ps + ((size_t)(b*8+s)*2+1)*Dd))[t] = q;
    }
}

// ---- finalize stats -> z ; also write cls row of lm (bf16) ----
__global__ __launch_bounds__(384) void k_statsfin(const float* __restrict__ x, const float* __restrict__ ps,
                                                  float* __restrict__ z, unsigned short* __restrict__ lm){
    int b = blockIdx.x, d = threadIdx.x;
    float sm = 0.f, sq = 0.f;
    for (int s = 0; s < 8; ++s){
        sm += ps[((size_t)(b*8+s)*2+0)*Dd + d];
        sq += ps[((size_t)(b*8+s)*2+1)*Dd + d];
    }
    float mean = sm*(1.0f/Nn);
    float var  = sq*(1.0f/Nn) - mean*mean;
    float cls  = x[(size_t)b*Nn*Dd + d];
    z[(size_t)b*CINc + d]        = cls;
    z[(size_t)b*CINc + Dd + d]   = mean;
    z[(size_t)b*CINc + 2*Dd + d] = var;
    lm[(size_t)b*Nn*Dd + d]      = f2bf(cls);   // n = 0 row
}

// ---- control MLP ----
__global__ __launch_bounds__(128) void k_mlp(const float* __restrict__ z, const float* __restrict__ w1, const float* __restrict__ b1,
    const float* __restrict__ w_rot, const float* __restrict__ b_rot,
    const float* __restrict__ w_rg, const float* __restrict__ b_rg,
    const float* __restrict__ w_lg, const float* __restrict__ b_lg,
    const float* __restrict__ w_sc, const float* __restrict__ b_sc,
    float* __restrict__ h, float* __restrict__ rc, float* __restrict__ rg, float* __restrict__ lg, float* __restrict__ sc){
    __shared__ float zs[1152];
    __shared__ float hs[128];
    int b = blockIdx.x, t = threadIdx.x;
    for (int c = t; c < CINc; c += Hh) zs[c] = z[(size_t)b*CINc + c];
    __syncthreads();
    float a = b1[t];
    const float* wrow = w1 + (size_t)t*CINc;
    for (int c = 0; c < CINc; ++c) a += zs[c]*wrow[c];
    float g = gelu_t(a);
    hs[t] = g;
    h[(size_t)b*Hh + t] = g;
    __syncthreads();
    if (t < 8){
        float acc = b_rot[t]; const float* w = w_rot + (size_t)t*Hh;
        for (int c = 0; c < Hh; ++c) acc += hs[c]*w[c];
        rc[b*8+t] = tanhf(acc);
    } else if (t == 8){
        float acc = b_rg[0];
        for (int c = 0; c < Hh; ++c) acc += hs[c]*w_rg[c];
        rg[b] = sigm(acc);
    } else if (t == 9){
        float acc = b_lg[0];
        for (int c = 0; c < Hh; ++c) acc += hs[c]*w_lg[c];
        lg[b] = sigm(acc);
    } else if (t < 18){
        int q = t-10; float acc = b_sc[q]; const float* w = w_sc + (size_t)q*Hh;
        for (int c = 0; c < Hh; ++c) acc += hs[c]*w[c];
        sc[b*8+q] = tanhf(acc);
    }
}

__global__ __launch_bounds__(384) void k_scalevec(const float* __restrict__ sc, const float* __restrict__ sbasis,
                                                  const float* __restrict__ sstr, float* __restrict__ scalev){
    int b = blockIdx.x, o = threadIdx.x;
    float acc = 0.f;
    for (int q = 0; q < 8; ++q) acc += sc[b*8+q]*sbasis[q*OUTo + o];
    scalev[(size_t)b*OUTo + o] = 1.0f + sstr[0]*tanhf(acc);
}

// ---- ||basis_k||_F^2 partials ----
__global__ __launch_bounds__(256) void k_normpart(const float* __restrict__ lb, const float* __restrict__ rb, float* __restrict__ np){
    int blk = blockIdx.x, k = blockIdx.y, t = threadIdx.x;
    int idx = blk*256 + t;
    int d = idx/Dd, e = idx - d*Dd;
    const float* Ld = lb + ((size_t)k*Dd + d)*Rr;
    const float* Re = rb + ((size_t)k*Dd + e)*Rr;
    const float* Rd = rb + ((size_t)k*Dd + d)*Rr;
    const float* Le = lb + ((size_t)k*Dd + e)*Rr;
    float v = 0.f;
    #pragma unroll
    for (int r = 0; r < Rr; ++r) v += Ld[r]*Re[r] - Rd[r]*Le[r];
    __shared__ float red[256];
    red[t] = v*v; __syncthreads();
    for (int sft = 128; sft > 0; sft >>= 1){ if (t < sft) red[t] += red[t+sft]; __syncthreads(); }
    if (t == 0) np[k*576 + blk] = red[0];
}

__global__ __launch_bounds__(64) void k_normfin(const float* __restrict__ np, float* __restrict__ n2){
    int k = blockIdx.x, t = threadIdx.x;
    float s = 0.f;
    for (int i = t; i < 576; i += 64) s += np[k*576 + i];
    for (int m = 32; m > 0; m >>= 1) s += __shfl_xor(s, m, 64);
    if (t == 0) n2[k] = s;
}

// ---- build P=[L|R] (f32 + bf16), Q=[R|L] ----
__global__ __launch_bounds__(256) void k_pq(const float* __restrict__ lb, const float* __restrict__ rb,
                                            float* __restrict__ P, float* __restrict__ Q, unsigned short* __restrict__ Pb){
    int idx = blockIdx.x*256 + threadIdx.x;   // < 49152
    int d = idx >> 7, j = idx & 127;
    int k = (j & 63) >> 3, r = j & 7;
    float lv = lb[((size_t)k*Dd + d)*Rr + r];
    float rv = rb[((size_t)k*Dd + d)*Rr + r];
    float pv = (j < 64) ? lv : rv;
    P[idx] = pv;
    Pb[idx] = f2bf(pv);
    Q[idx] = (j < 64) ? rv : lv;
}

// ---- G = Q^T P (128x128) ----
__global__ __launch_bounds__(128) void k_gram(const float* __restrict__ P, const float* __restrict__ Q, float* __restrict__ G){
    int i = blockIdx.x, j = threadIdx.x;
    float acc = 0.f;
    for (int d = 0; d < Dd; ++d) acc += Q[d*128 + i]*P[d*128 + j];
    G[i*128 + j] = acc;
}

// ---- QW = Q^T Wsh^T (128 x 384) ----
__global__ __launch_bounds__(384) void k_qw(const float* __restrict__ Q, const float* __restrict__ Wsh, float* __restrict__ QW){
    int i = blockIdx.x, o = threadIdx.x;
    float acc = 0.f;
    for (int d = 0; d < Dd; ++d) acc += Q[d*128 + i]*Wsh[(size_t)o*Dd + d];
    QW[(size_t)i*OUTo + o] = acc;
}

// ---- Neumann iteration for (I-DG)^{-1} D (I+GD) ----
__global__ __launch_bounds__(256) void k_neumann(const float* __restrict__ G, const float* __restrict__ rc, const float* __restrict__ n2,
                                                 const float* __restrict__ Xin, float* __restrict__ Xout, int init){
    __shared__ float ds[128];
    __shared__ float GsT[128*130];
    __shared__ float Xs[16*130];
    int jg = blockIdx.x, b = blockIdx.y, t = threadIdx.x;
    int j0 = jg*16;
    if (t < 128){
        int k = (t & 63) >> 3;
        float nrm = fmaxf(sqrtf(n2[k]), 1e-6f);
        float al = 0.5f*rc[b*8+k]/nrm;
        ds[t] = (t < 64) ? al : -al;
    }
    for (int lin = t; lin < 16384; lin += 256){
        int i = lin >> 7, m = lin & 127;
        GsT[m*130 + i] = G[lin];
    }
    __syncthreads();
    for (int u = 0; u < 8; ++u){
        int lin = t + 256*u;
        int jl = lin >> 7, m = lin & 127;
        int j = j0 + jl;
        float v;
        if (init) v = ds[m]*GsT[j*130 + m]*ds[j] + ((m == j) ? ds[m] : 0.f);
        else      v = Xin[((size_t)b*128 + j)*128 + m];
        Xs[jl*130 + m] = v;
    }
    __syncthreads();
    int jl = t >> 4, il = t & 15;
    int j = j0 + jl;
    float dj = ds[j];
    const float* xc = &Xs[jl*130];
    #pragma unroll
    for (int s = 0; s < 8; ++s){
        int i = il + 16*s;
        float acc = 0.f;
        #pragma unroll 4
        for (int m = 0; m < 128; ++m) acc += GsT[m*130 + i]*xc[m];
        float di = ds[i];
        float outv = di*(GsT[j*130 + i]*dj + acc) + ((i == j) ? di : 0.f);
        Xout[((size_t)b*128 + j)*128 + i] = outv;
    }
}

// ---- Ep = rot_gate * (D + X) ----
__global__ __launch_bounds__(128) void k_ep(const float* __restrict__ X, const float* __restrict__ rc, const float* __restrict__ n2,
                                            const float* __restrict__ rg, float* __restrict__ Ep){
    int i = blockIdx.x, b = blockIdx.y, j = threadIdx.x;
    float v = X[((size_t)b*128 + j)*128 + i];
    if (i == j){
        int k = (i & 63) >> 3;
        float nrm = fmaxf(sqrtf(n2[k]), 1e-6f);
        float al = 0.5f*rc[b*8+k]/nrm;
        v += (i < 64) ? al : -al;
    }
    Ep[((size_t)b*128 + i)*128 + j] = rg[b]*v;
}

// ---- ZT[b][o][m] = (Ep @ QW)^T in bf16 ----
__global__ __launch_bounds__(384) void k_zmatT(const float* __restrict__ Ep, const float* __restrict__ QW, unsigned short* __restrict__ ZT){
    __shared__ float Es[4*128];
    int ig = blockIdx.x, b = blockIdx.y, t = threadIdx.x;
    int i0 = ig*4;
    for (int lin = t; lin < 512; lin += 384)
        Es[lin] = Ep[((size_t)b*128 + i0 + (lin >> 7))*128 + (lin & 127)];
    __syncthreads();
    float a0=0.f, a1=0.f, a2=0.f, a3=0.f;
    for (int m = 0; m < 128; ++m){
        float qw = QW[(size_t)m*OUTo + t];
        a0 += Es[m]*qw; a1 += Es[128+m]*qw; a2 += Es[256+m]*qw; a3 += Es[384+m]*qw;
    }
    ushort4 uv;
    uv.x = f2bf(a0); uv.y = f2bf(a1); uv.z = f2bf(a2); uv.w = f2bf(a3);
    *(ushort4*)(ZT + ((size_t)b*OUTo + t)*128 + i0) = uv;
}

// ---- WbT[b][o][d] = Wsh[o][d] + sum_m ZT[b][o][m]*P[d][m]   (MFMA NT, bf16 out) ----
__global__ __launch_bounds__(256) void k_wbt(const unsigned short* __restrict__ ZT, const unsigned short* __restrict__ Pb,
                                             const float* __restrict__ Wsh, unsigned short* __restrict__ WbT){
    __shared__ short8 As[256];
    __shared__ short8 Bs[256];
    int b = blockIdx.y;
    int mt = blockIdx.x/6, nt2 = blockIdx.x%6;
    int m0 = mt*64, n0 = nt2*64;        // m0: o-rows, n0: d-cols
    int t = threadIdx.x;
    int w = t>>6, l = t&63;
    int wr = w>>1, wc = w&1;
    const unsigned short* Ab = ZT + (size_t)b*OUTo*128;
    int lrow = t>>2, lseg = t&3;
    f32x4 acc[2][2];
    #pragma unroll
    for (int mi=0;mi<2;++mi)
        #pragma unroll
        for (int ni=0;ni<2;++ni)
            #pragma unroll
            for (int q=0;q<4;++q) acc[mi][ni][q] = 0.f;
    for (int kt = 0; kt < 4; ++kt){
        int k0 = kt*32;
        short8 av = *(const short8*)(Ab + (size_t)(m0+lrow)*128 + k0 + lseg*8);
        short8 bv = *(const short8*)(Pb + (size_t)(n0+lrow)*128 + k0 + lseg*8);
        __syncthreads();
        As[lseg*64 + lrow] = av;
        Bs[lseg*64 + lrow] = bv;
        __syncthreads();
        short8 a0 = As[(l>>4)*64 + wr*32 + (l&15)];
        short8 a1 = As[(l>>4)*64 + wr*32 + 16 + (l&15)];
        short8 b0 = Bs[(l>>4)*64 + wc*32 + (l&15)];
        short8 b1 = Bs[(l>>4)*64 + wc*32 + 16 + (l&15)];
        acc[0][0] = MFMA_BF16(a0, b0, acc[0][0]);
        acc[0][1] = MFMA_BF16(a0, b1, acc[0][1]);
        acc[1][0] = MFMA_BF16(a1, b0, acc[1][0]);
        acc[1][1] = MFMA_BF16(a1, b1, acc[1][1]);
    }
    unsigned short* Wo = WbT + (size_t)b*OUTo*Dd;
    #pragma unroll
    for (int mi=0;mi<2;++mi){
        #pragma unroll
        for (int ni=0;ni<2;++ni){
            int col = n0 + wc*32 + ni*16 + (l&15);     // d
            #pragma unroll
            for (int r=0;r<4;++r){
                int row = m0 + wr*32 + mi*16 + (l>>4)*4 + r;  // o
                float v = Wsh[(size_t)row*Dd + col] + acc[mi][ni][r];
                Wo[(size_t)row*Dd + col] = f2bf(v);
            }
        }
    }
}

// ---- lm patches: float4-vectorized dwconv3x3 + gate blend, bf16 out ----
// block: (gy 0..31, b); 384 threads: dq = t%96 (float4 col), gxg = t/96
__global__ __launch_bounds__(384) void k_lm(const float* __restrict__ x, const float* __restrict__ kw,
                                            const float* __restrict__ lg, unsigned short* __restrict__ lm){
    __shared__ float kws[9*384];        // kws[tap*384 + d]
    int gy = blockIdx.x, b = blockIdx.y, t = threadIdx.x;
    for (int i = t; i < 3456; i += 384){
        int d = i % 384, tap = i / 384;
        kws[tap*384 + d] = kw[d*9 + tap];
    }
    __syncthreads();
    int dq = t % 96, gxg = t / 96;
    float lgb = lg[b];
    const float4* xb = (const float4*)(x + (size_t)b*Nn*Dd);
    unsigned short* lmb = lm + (size_t)b*Nn*Dd;
    #pragma unroll
    for (int u = 0; u < 8; ++u){
        int gx = gxg + 4*u;
        int n = 1 + (gy << 5) + gx;
        float4 xc = xb[(size_t)n*96 + dq];
        float ax = 0.f, ay = 0.f, az = 0.f, aw = 0.f;
        #pragma unroll
        for (int ky = 0; ky < 3; ++ky){
            int yy = gy + ky - 1;
            if ((unsigned)yy < 32u){
                #pragma unroll
                for (int kx = 0; kx < 3; ++kx){
                    int xx = gx + kx - 1;
                    if ((unsigned)xx < 32u){
                        float4 xv = xb[(size_t)(1 + (yy << 5) + xx)*96 + dq];
                        const float4 kv = *(const float4*)(&kws[(ky*3+kx)*384 + dq*4]);
                        ax += xv.x*kv.x; ay += xv.y*kv.y; az += xv.z*kv.z; aw += xv.w*kv.w;
                    }
                }
            }
        }
        ushort4 o4;
        o4.x = f2bf(xc.x + lgb*(ax - xc.x));
        o4.y = f2bf(xc.y + lgb*(ay - xc.y));
        o4.z = f2bf(xc.z + lgb*(az - xc.z));
        o4.w = f2bf(xc.w + lgb*(aw - xc.w));
        *(ushort4*)(lmb + (size_t)n*Dd + dq*4) = o4;
    }
}

// ---- out = (lm_bf16 @ Wb + bias)*scale via Bt = WbT  (MFMA NT) ----
__global__ __launch_bounds__(256) void k_gemm_nt(const unsigned short* __restrict__ lm, const unsigned short* __restrict__ WbT,
                                                 const float* __restrict__ bias, const float* __restrict__ scalev,
                                                 float* __restrict__ out){
    __shared__ short8 As[256];
    __shared__ short8 Bs[256];
    int b = blockIdx.y;
    int mt = blockIdx.x/6, ot = blockIdx.x%6;
    int n0 = mt*64, o0 = ot*64;
    int t = threadIdx.x;
    int w = t>>6, l = t&63;
    int wr = w>>1, wc = w&1;
    const unsigned short* Ab = lm + (size_t)b*Nn*Dd;
    const unsigned short* Bt = WbT + (size_t)b*OUTo*Dd;
    int lrow = t>>2, lseg = t&3;
    f32x4 acc[2][2];
    #pragma unroll
    for (int mi=0;mi<2;++mi)
        #pragma unroll
        for (int ni=0;ni<2;++ni)
            #pragma unroll
            for (int q=0;q<4;++q) acc[mi][ni][q] = 0.f;
    for (int kt = 0; kt < 12; ++kt){
        int k0 = kt*32;
        short8 av = {0,0,0,0,0,0,0,0};
        int arow = n0 + lrow;
        if (arow < Nn) av = *(const short8*)(Ab + (size_t)arow*Dd + k0 + lseg*8);
        short8 bv = *(const short8*)(Bt + (size_t)(o0+lrow)*Dd + k0 + lseg*8);
        __syncthreads();
        As[lseg*64 + lrow] = av;
        Bs[lseg*64 + lrow] = bv;
        __syncthreads();
        short8 a0 = As[(l>>4)*64 + wr*32 + (l&15)];
        short8 a1 = As[(l>>4)*64 + wr*32 + 16 + (l&15)];
        short8 b0 = Bs[(l>>4)*64 + wc*32 + (l&15)];
        short8 b1 = Bs[(l>>4)*64 + wc*32 + 16 + (l&15)];
        acc[0][0] = MFMA_BF16(a0, b0, acc[0][0]);
        acc[0][1] = MFMA_BF16(a0, b1, acc[0][1]);
        acc[1][0] = MFMA_BF16(a1, b0, acc[1][0]);
        acc[1][1] = MFMA_BF16(a1, b1, acc[1][1]);
    }
    const float* sv = scalev + (size_t)b*OUTo;
    #pragma unroll
    for (int mi=0;mi<2;++mi){
        #pragma unroll
        for (int ni=0;ni<2;++ni){
            int col = o0 + wc*32 + ni*16 + (l&15);
            float svv = sv[col], bvv = bias[col];
            #pragma unroll
            for (int r=0;r<4;++r){
                int row = n0 + wr*32 + mi*16 + (l>>4)*4 + r;
                if (row < Nn)
                    out[((size_t)b*Nn + row)*OUTo + col] = svv*(bvv + acc[mi][ni][r]);
            }
        }
    }
}

extern "C" void kernel_launch(void* const* d_in, const int* in_sizes, int n_in,
                              void* d_out, int out_size, void* d_ws, size_t ws_size,
                              hipStream_t stream){
    const float* x     = (const float*)d_in[0];
    const float* Wsh   = (const float*)d_in[1];
    const float* bias  = (const float*)d_in[2];
    const float* lb    = (const float*)d_in[3];
    const float* rb    = (const float*)d_in[4];
    const float* sbasis= (const float*)d_in[5];
    const float* sstr  = (const float*)d_in[6];
    const float* kw    = (const float*)d_in[7];
    const float* w1    = (const float*)d_in[8];
    const float* b1    = (const float*)d_in[9];
    const float* w_rot = (const float*)d_in[10];
    const float* b_rot = (const float*)d_in[11];
    const float* w_rg  = (const float*)d_in[12];
    const float* b_rg  = (const float*)d_in[13];
    const float* w_lg  = (const float*)d_in[14];
    const float* b_lg  = (const float*)d_in[15];
    const float* w_sc  = (const float*)d_in[16];
    const float* b_sc  = (const float*)d_in[17];
    float* out = (float*)d_out;
    float* ws  = (float*)d_ws;

    float* ps     = ws + OFF_PSTAT;
    float* z      = ws + OFF_Z;
    float* h      = ws + OFF_H;
    float* rc     = ws + OFF_RC;
    float* rg     = ws + OFF_RG;
    float* lg     = ws + OFF_LG;
    float* sc     = ws + OFF_SC;
    float* scalev = ws + OFF_SCALE;
    float* np     = ws + OFF_NP;
    float* n2     = ws + OFF_N2;
    float* P      = ws + OFF_P;
    float* Q      = ws + OFF_Q;
    float* G      = ws + OFF_G;
    float* QW     = ws + OFF_QW;
    unsigned short* Pb  = (unsigned short*)(ws + OFF_PB);
    float* Ep     = ws + OFF_EP;
    float* Xa     = ws + OFF_XA;
    float* Xb     = ws + OFF_XB;
    unsigned short* ZT  = (unsigned short*)(ws + OFF_ZT);
    unsigned short* WbT = (unsigned short*)(ws + OFF_WBT);
    unsigned short* lmb = (unsigned short*)(ws + OFF_LM);

    k_stats   <<<dim3(8, Bb), 384, 0, stream>>>(x, ps);
    k_statsfin<<<Bb, 384, 0, stream>>>(x, ps, z, lmb);
    k_mlp     <<<Bb, 128, 0, stream>>>(z, w1, b1, w_rot, b_rot, w_rg, b_rg, w_lg, b_lg, w_sc, b_sc,
                                       h, rc, rg, lg, sc);
    k_scalevec<<<Bb, 384, 0, stream>>>(sc, sbasis, sstr, scalev);
    k_normpart<<<dim3(576, Kk), 256, 0, stream>>>(lb, rb, np);
    k_normfin <<<Kk, 64, 0, stream>>>(np, n2);
    k_pq      <<<192, 256, 0, stream>>>(lb, rb, P, Q, Pb);
    k_gram    <<<128, 128, 0, stream>>>(P, Q, G);
    k_qw      <<<128, 384, 0, stream>>>(Q, Wsh, QW);
    k_neumann <<<dim3(8, Bb), 256, 0, stream>>>(G, rc, n2, Xa, Xb, 1);
    k_neumann <<<dim3(8, Bb), 256, 0, stream>>>(G, rc, n2, Xb, Xa, 0);
    k_neumann <<<dim3(8, Bb), 256, 0, stream>>>(G, rc, n2, Xa, Xb, 0);
    k_neumann <<<dim3(8, Bb), 256, 0, stream>>>(G, rc, n2, Xb, Xa, 0);
    k_ep      <<<dim3(128, Bb), 128, 0, stream>>>(Xa, rc, n2, rg, Ep);
    k_zmatT   <<<dim3(32, Bb), 384, 0, stream>>>(Ep, QW, ZT);
    k_wbt     <<<dim3(36, Bb), 256, 0, stream>>>(ZT, Pb, Wsh, WbT);
    k_lm      <<<dim3(32, Bb), 384, 0, stream>>>(x, kw, lg, lmb);
    k_gemm_nt <<<dim3(102, Bb), 256, 0, stream>>>(lmb, WbT, bias, scalev, out);
}

// Round 4
// 354.703 us; speedup vs baseline: 2.9629x; 1.1576x over previous
//
#include <hip/hip_runtime.h>
#include <hip/hip_bf16.h>
#include <math.h>

// B=64 N=1025 D=384 K=8 R=8 KS=8 H=128 CIN=1152 OUT=384 ; rank m = 2*K*R = 128
static const int Bb = 64, Nn = 1025, Dd = 384, Kk = 8, Rr = 8, Hh = 128, CINc = 1152, OUTo = 384;

// ---- workspace layout (float offsets); ~91 MB total (R1 proved >=150 MB available) ----
#define OFF_PSTAT 0u          // 393216
#define OFF_Z     393216u     // 73728
#define OFF_H     466944u     // 8192
#define OFF_RC    475136u     // 512
#define OFF_RG    475648u     // 64
#define OFF_LG    475712u     // 64
#define OFF_SC    475776u     // 512
#define OFF_SCALE 476288u     // 24576
#define OFF_NP    500864u     // 4608 (unused now)
#define OFF_N2    505472u     // 128
#define OFF_P     505600u     // 49152 (f32)
#define OFF_Q     554752u     // 49152 (f32)
#define OFF_G     603904u     // 16384
#define OFF_QW    620288u     // 49152 (f32)
#define OFF_PB    669440u     // 24576  (bf16 384x128)
#define OFF_EP    694016u     // 1048576
#define OFF_ZT    3839744u    // 1572864 (bf16 64x384x128)
#define OFF_WBT   5412608u    // 4718592 (bf16 64x384x384)
#define OFF_LM    10131200u   // 12595200 (bf16 64x1025x384) + 24384 pad (128 garbage rows for GEMM tile overrun)

typedef __attribute__((ext_vector_type(8))) short short8;
typedef __attribute__((ext_vector_type(8))) __bf16 bf16x8;
typedef __attribute__((ext_vector_type(4))) float f32x4;

#define MFMA_BF16(a,b,c) __builtin_amdgcn_mfma_f32_16x16x32_bf16( \
    __builtin_bit_cast(bf16x8,(a)), __builtin_bit_cast(bf16x8,(b)), (c), 0, 0, 0)

// async global->LDS, 16B per lane; LDS dest is wave-uniform base + lane*16 (linear)
#define GLDS16(gp, lp) __builtin_amdgcn_global_load_lds( \
    (__attribute__((address_space(1))) void*)(gp), \
    (__attribute__((address_space(3))) void*)(lp), 16, 0, 0)

__device__ __forceinline__ float gelu_t(float v){
    float u = 0.7978845608028654f*(v + 0.044715f*v*v*v);
    return 0.5f*v*(1.0f + tanhf(u));
}
__device__ __forceinline__ float sigm(float v){ return 1.0f/(1.0f+expf(-v)); }
__device__ __forceinline__ unsigned short f2bf(float v){
    return __builtin_bit_cast(unsigned short, __float2bfloat16(v));
}

// ---- per-(b,d) token stats, float4-vectorized, 8 token slices ----
__global__ __launch_bounds__(384) void k_stats(const float* __restrict__ x, float* __restrict__ ps){
    int s = blockIdx.x, b = blockIdx.y, t = threadIdx.x;
    int dq = t % 96, ng = t / 96;
    int n0 = s*129, n1 = n0+129 < Nn ? n0+129 : Nn;
    const float4* xb = (const float4*)(x + (size_t)b*Nn*Dd);
    float4 sm = make_float4(0.f,0.f,0.f,0.f), sq = make_float4(0.f,0.f,0.f,0.f);
    for (int n = n0+ng; n < n1; n += 4){
        float4 v = xb[(size_t)n*96 + dq];
        sm.x += v.x; sm.y += v.y; sm.z += v.z; sm.w += v.w;
        sq.x += v.x*v.x; sq.y += v.y*v.y; sq.z += v.z*v.z; sq.w += v.w*v.w;
    }
    __shared__ float4 smS[384];
    __shared__ float4 sqS[384];
    smS[t] = sm; sqS[t] = sq;
    __syncthreads();
    if (t < 96){
        float4 a0 = smS[t], a1 = smS[t+96], a2 = smS[t+192], a3 = smS[t+288];
        float4 q0 = sqS[t], q1 = sqS[t+96], q2 = sqS[t+192], q3 = sqS[t+288];
        float4 a = make_float4(a0.x+a1.x+a2.x+a3.x, a0.y+a1.y+a2.y+a3.y, a0.z+a1.z+a2.z+a3.z, a0.w+a1.w+a2.w+a3.w);
        float4 q = make_float4(q0.x+q1.x+q2.x+q3.x, q0.y+q1.y+q2.y+q3.y, q0.z+q1.z+q2.z+q3.z, q0.w+q1.w+q2.w+q3.w);
        ((float4*)(ps + ((size_t)(b*8+s)*2+0)*Dd))[t] = a;
        ((float4*)(ps + ((size_t)(b*8+s)*2+1)*Dd))[t] = q;
    }
}

// ---- finalize stats -> z ; also write cls row of lm (bf16) ----
__global__ __launch_bounds__(384) void k_statsfin(const float* __restrict__ x, const float* __restrict__ ps,
                                                  float* __restrict__ z, unsigned short* __restrict__ lm){
    int b = blockIdx.x, d = threadIdx.x;
    float sm = 0.f, sq = 0.f;
    for (int s = 0; s < 8; ++s){
        sm += ps[((size_t)(b*8+s)*2+0)*Dd + d];
        sq += ps[((size_t)(b*8+s)*2+1)*Dd + d];
    }
    float mean = sm*(1.0f/Nn);
    float var  = sq*(1.0f/Nn) - mean*mean;
    float cls  = x[(size_t)b*Nn*Dd + d];
    z[(size_t)b*CINc + d]        = cls;
    z[(size_t)b*CINc + Dd + d]   = mean;
    z[(size_t)b*CINc + 2*Dd + d] = var;
    lm[(size_t)b*Nn*Dd + d]      = f2bf(cls);
}

// ---- control MLP ----
__global__ __launch_bounds__(128) void k_mlp(const float* __restrict__ z, const float* __restrict__ w1, const float* __restrict__ b1,
    const float* __restrict__ w_rot, const float* __restrict__ b_rot,
    const float* __restrict__ w_rg, const float* __restrict__ b_rg,
    const float* __restrict__ w_lg, const float* __restrict__ b_lg,
    const float* __restrict__ w_sc, const float* __restrict__ b_sc,
    float* __restrict__ h, float* __restrict__ rc, float* __restrict__ rg, float* __restrict__ lg, float* __restrict__ sc){
    __shared__ float zs[1152];
    __shared__ float hs[128];
    int b = blockIdx.x, t = threadIdx.x;
    for (int c = t; c < CINc; c += Hh) zs[c] = z[(size_t)b*CINc + c];
    __syncthreads();
    float a = b1[t];
    const float* wrow = w1 + (size_t)t*CINc;
    for (int c = 0; c < CINc; ++c) a += zs[c]*wrow[c];
    float g = gelu_t(a);
    hs[t] = g;
    h[(size_t)b*Hh + t] = g;
    __syncthreads();
    if (t < 8){
        float acc = b_rot[t]; const float* w = w_rot + (size_t)t*Hh;
        for (int c = 0; c < Hh; ++c) acc += hs[c]*w[c];
        rc[b*8+t] = tanhf(acc);
    } else if (t == 8){
        float acc = b_rg[0];
        for (int c = 0; c < Hh; ++c) acc += hs[c]*w_rg[c];
        rg[b] = sigm(acc);
    } else if (t == 9){
        float acc = b_lg[0];
        for (int c = 0; c < Hh; ++c) acc += hs[c]*w_lg[c];
        lg[b] = sigm(acc);
    } else if (t < 18){
        int q = t-10; float acc = b_sc[q]; const float* w = w_sc + (size_t)q*Hh;
        for (int c = 0; c < Hh; ++c) acc += hs[c]*w[c];
        sc[b*8+q] = tanhf(acc);
    }
}

__global__ __launch_bounds__(384) void k_scalevec(const float* __restrict__ sc, const float* __restrict__ sbasis,
                                                  const float* __restrict__ sstr, float* __restrict__ scalev){
    int b = blockIdx.x, o = threadIdx.x;
    float acc = 0.f;
    for (int q = 0; q < 8; ++q) acc += sc[b*8+q]*sbasis[q*OUTo + o];
    scalev[(size_t)b*OUTo + o] = 1.0f + sstr[0]*tanhf(acc);
}

// ---- ||basis_k||_F^2 = 2(tr(A B) - tr(C^2)), A=L^TL, B=R^TR, C=L^TR (8x8 grams) ----
__global__ __launch_bounds__(64) void k_norm(const float* __restrict__ lb, const float* __restrict__ rb, float* __restrict__ n2){
    int k = blockIdx.x, t = threadIdx.x;
    int r = t >> 3, s = t & 7;
    const float* L = lb + (size_t)k*Dd*Rr;
    const float* R = rb + (size_t)k*Dd*Rr;
    float a = 0.f, bsum = 0.f, c = 0.f, c2 = 0.f;
    for (int d = 0; d < Dd; ++d){
        float lr = L[d*8+r], ls = L[d*8+s], rr = R[d*8+r], rs = R[d*8+s];
        a += lr*ls; bsum += rr*rs; c += lr*rs; c2 += ls*rr;
    }
    float contrib = a*bsum - c*c2;
    for (int m = 32; m > 0; m >>= 1) contrib += __shfl_xor(contrib, m, 64);
    if (t == 0) n2[k] = 2.f*contrib;
}

// ---- build P=[L|R] (f32 + bf16), Q=[R|L] ----
__global__ __launch_bounds__(256) void k_pq(const float* __restrict__ lb, const float* __restrict__ rb,
                                            float* __restrict__ P, float* __restrict__ Q, unsigned short* __restrict__ Pb){
    int idx = blockIdx.x*256 + threadIdx.x;   // < 49152
    int d = idx >> 7, j = idx & 127;
    int k = (j & 63) >> 3, r = j & 7;
    float lv = lb[((size_t)k*Dd + d)*Rr + r];
    float rv = rb[((size_t)k*Dd + d)*Rr + r];
    float pv = (j < 64) ? lv : rv;
    P[idx] = pv;
    Pb[idx] = f2bf(pv);
    Q[idx] = (j < 64) ? rv : lv;
}

// ---- G = Q^T P (128x128) ----
__global__ __launch_bounds__(128) void k_gram(const float* __restrict__ P, const float* __restrict__ Q, float* __restrict__ G){
    int i = blockIdx.x, j = threadIdx.x;
    float acc = 0.f;
    for (int d = 0; d < Dd; ++d) acc += Q[d*128 + i]*P[d*128 + j];
    G[i*128 + j] = acc;
}

// ---- QW = Q^T Wsh^T (128 x 384) ----
__global__ __launch_bounds__(384) void k_qw(const float* __restrict__ Q, const float* __restrict__ Wsh, float* __restrict__ QW){
    int i = blockIdx.x, o = threadIdx.x;
    float acc = 0.f;
    for (int d = 0; d < Dd; ++d) acc += Q[d*128 + i]*Wsh[(size_t)o*Dd + d];
    QW[(size_t)i*OUTo + o] = acc;
}

// ---- fused Cayley/Neumann: X = sum_{k<=2} (DG)^k B0, Ep = rg*(D + X)  ----
// one block per batch; G transposed in LDS once; X LDS-resident; 4x8 register tiles
__global__ __launch_bounds__(512) void k_cayley(const float* __restrict__ G, const float* __restrict__ rc,
                                                const float* __restrict__ n2, const float* __restrict__ rg,
                                                float* __restrict__ Ep){
    __shared__ float GT[128*128];   // GT[m][i] = G[i][m]
    __shared__ float Xs[128*128];   // X[i][j]
    int b = blockIdx.x, t = threadIdx.x;
    for (int lin = t; lin < 16384; lin += 512){
        int i = lin >> 7, m = lin & 127;
        GT[m*128 + i] = G[lin];
    }
    int j0 = (t & 15)*8, i0 = (t >> 4)*4;
    float dj[8], di[4];
    #pragma unroll
    for (int u = 0; u < 8; ++u){
        int j = j0+u; int k = (j&63)>>3;
        float nrm = fmaxf(sqrtf(n2[k]), 1e-6f);
        float al = 0.5f*rc[b*8+k]/nrm;
        dj[u] = (j < 64) ? al : -al;
    }
    #pragma unroll
    for (int u = 0; u < 4; ++u){
        int i = i0+u; int k = (i&63)>>3;
        float nrm = fmaxf(sqrtf(n2[k]), 1e-6f);
        float al = 0.5f*rc[b*8+k]/nrm;
        di[u] = (i < 64) ? al : -al;
    }
    __syncthreads();
    // B0[i][j] = di*G[i][j]*dj + delta*di ; G[i][j] = GT[j][i]
    float B0[4][8], acc[4][8];
    #pragma unroll
    for (int ui = 0; ui < 4; ++ui)
        #pragma unroll
        for (int uj = 0; uj < 8; ++uj){
            int i = i0+ui, j = j0+uj;
            float g = GT[j*128 + i];
            B0[ui][uj] = di[ui]*g*dj[uj] + ((i==j) ? di[ui] : 0.f);
        }
    #pragma unroll
    for (int ui = 0; ui < 4; ++ui)
        #pragma unroll
        for (int uj = 0; uj < 8; ++uj)
            Xs[(i0+ui)*128 + j0+uj] = B0[ui][uj];
    __syncthreads();
    for (int pass = 0; pass < 2; ++pass){
        #pragma unroll
        for (int ui = 0; ui < 4; ++ui)
            #pragma unroll
            for (int uj = 0; uj < 8; ++uj) acc[ui][uj] = 0.f;
        for (int m = 0; m < 128; ++m){
            float4 g4 = *(const float4*)&GT[m*128 + i0];
            float4 xa = *(const float4*)&Xs[m*128 + j0];
            float4 xb = *(const float4*)&Xs[m*128 + j0 + 4];
            float gi[4] = {g4.x, g4.y, g4.z, g4.w};
            float xv[8] = {xa.x, xa.y, xa.z, xa.w, xb.x, xb.y, xb.z, xb.w};
            #pragma unroll
            for (int ui = 0; ui < 4; ++ui)
                #pragma unroll
                for (int uj = 0; uj < 8; ++uj)
                    acc[ui][uj] += gi[ui]*xv[uj];
        }
        if (pass == 0){
            __syncthreads();
            #pragma unroll
            for (int ui = 0; ui < 4; ++ui)
                #pragma unroll
                for (int uj = 0; uj < 8; ++uj)
                    Xs[(i0+ui)*128 + j0+uj] = B0[ui][uj] + di[ui]*acc[ui][uj];
            __syncthreads();
        }
    }
    float rgb = rg[b];
    #pragma unroll
    for (int ui = 0; ui < 4; ++ui){
        int i = i0+ui;
        float o[8];
        #pragma unroll
        for (int uj = 0; uj < 8; ++uj){
            int j = j0+uj;
            float x2 = B0[ui][uj] + di[ui]*acc[ui][uj];
            o[uj] = rgb*(x2 + ((i==j) ? di[ui] : 0.f));
        }
        float4* ep4 = (float4*)(Ep + ((size_t)b*128 + i)*128 + j0);
        ep4[0] = make_float4(o[0], o[1], o[2], o[3]);
        ep4[1] = make_float4(o[4], o[5], o[6], o[7]);
    }
}

// ---- ZT[b][o][m] = (Ep @ QW)^T in bf16 ----
__global__ __launch_bounds__(384) void k_zmatT(const float* __restrict__ Ep, const float* __restrict__ QW, unsigned short* __restrict__ ZT){
    __shared__ float Es[4*128];
    int ig = blockIdx.x, b = blockIdx.y, t = threadIdx.x;
    int i0 = ig*4;
    for (int lin = t; lin < 512; lin += 384)
        Es[lin] = Ep[((size_t)b*128 + i0 + (lin >> 7))*128 + (lin & 127)];
    __syncthreads();
    float a0=0.f, a1=0.f, a2=0.f, a3=0.f;
    for (int m = 0; m < 128; ++m){
        float qw = QW[(size_t)m*OUTo + t];
        a0 += Es[m]*qw; a1 += Es[128+m]*qw; a2 += Es[256+m]*qw; a3 += Es[384+m]*qw;
    }
    ushort4 uv;
    uv.x = f2bf(a0); uv.y = f2bf(a1); uv.z = f2bf(a2); uv.w = f2bf(a3);
    *(ushort4*)(ZT + ((size_t)b*OUTo + t)*128 + i0) = uv;
}

// ---- WbT[b][o][d] = Wsh[o][d] + sum_m ZT[b][o][m]*P[d][m]   (MFMA NT, bf16 out) ----
__global__ __launch_bounds__(256) void k_wbt(const unsigned short* __restrict__ ZT, const unsigned short* __restrict__ Pb,
                                             const float* __restrict__ Wsh, unsigned short* __restrict__ WbT){
    __shared__ short8 As[256];
    __shared__ short8 Bs[256];
    int b = blockIdx.y;
    int mt = blockIdx.x/6, nt2 = blockIdx.x%6;
    int m0 = mt*64, n0 = nt2*64;
    int t = threadIdx.x;
    int w = t>>6, l = t&63;
    int wr = w>>1, wc = w&1;
    const unsigned short* Ab = ZT + (size_t)b*OUTo*128;
    int lrow = t>>2, lseg = t&3;
    f32x4 acc[2][2];
    #pragma unroll
    for (int mi=0;mi<2;++mi)
        #pragma unroll
        for (int ni=0;ni<2;++ni)
            #pragma unroll
            for (int q=0;q<4;++q) acc[mi][ni][q] = 0.f;
    for (int kt = 0; kt < 4; ++kt){
        int k0 = kt*32;
        short8 av = *(const short8*)(Ab + (size_t)(m0+lrow)*128 + k0 + lseg*8);
        short8 bv = *(const short8*)(Pb + (size_t)(n0+lrow)*128 + k0 + lseg*8);
        __syncthreads();
        As[lseg*64 + lrow] = av;
        Bs[lseg*64 + lrow] = bv;
        __syncthreads();
        short8 a0 = As[(l>>4)*64 + wr*32 + (l&15)];
        short8 a1 = As[(l>>4)*64 + wr*32 + 16 + (l&15)];
        short8 b0 = Bs[(l>>4)*64 + wc*32 + (l&15)];
        short8 b1 = Bs[(l>>4)*64 + wc*32 + 16 + (l&15)];
        acc[0][0] = MFMA_BF16(a0, b0, acc[0][0]);
        acc[0][1] = MFMA_BF16(a0, b1, acc[0][1]);
        acc[1][0] = MFMA_BF16(a1, b0, acc[1][0]);
        acc[1][1] = MFMA_BF16(a1, b1, acc[1][1]);
    }
    unsigned short* Wo = WbT + (size_t)b*OUTo*Dd;
    #pragma unroll
    for (int mi=0;mi<2;++mi){
        #pragma unroll
        for (int ni=0;ni<2;++ni){
            int col = n0 + wc*32 + ni*16 + (l&15);
            #pragma unroll
            for (int r=0;r<4;++r){
                int row = m0 + wr*32 + mi*16 + (l>>4)*4 + r;
                float v = Wsh[(size_t)row*Dd + col] + acc[mi][ni][r];
                Wo[(size_t)row*Dd + col] = f2bf(v);
            }
        }
    }
}

// ---- lm patches: float4-vectorized dwconv3x3 + gate blend, bf16 out ----
__global__ __launch_bounds__(384) void k_lm(const float* __restrict__ x, const float* __restrict__ kw,
                                            const float* __restrict__ lg, unsigned short* __restrict__ lm){
    __shared__ float kws[9*384];
    int gy = blockIdx.x, b = blockIdx.y, t = threadIdx.x;
    for (int i = t; i < 3456; i += 384){
        int d = i % 384, tap = i / 384;
        kws[tap*384 + d] = kw[d*9 + tap];
    }
    __syncthreads();
    int dq = t % 96, gxg = t / 96;
    float lgb = lg[b];
    const float4* xb = (const float4*)(x + (size_t)b*Nn*Dd);
    unsigned short* lmb = lm + (size_t)b*Nn*Dd;
    #pragma unroll
    for (int u = 0; u < 8; ++u){
        int gx = gxg + 4*u;
        int n = 1 + (gy << 5) + gx;
        float4 xc = xb[(size_t)n*96 + dq];
        float ax = 0.f, ay = 0.f, az = 0.f, aw = 0.f;
        #pragma unroll
        for (int ky = 0; ky < 3; ++ky){
            int yy = gy + ky - 1;
            if ((unsigned)yy < 32u){
                #pragma unroll
                for (int kx = 0; kx < 3; ++kx){
                    int xx = gx + kx - 1;
                    if ((unsigned)xx < 32u){
                        float4 xv = xb[(size_t)(1 + (yy << 5) + xx)*96 + dq];
                        const float4 kv = *(const float4*)(&kws[(ky*3+kx)*384 + dq*4]);
                        ax += xv.x*kv.x; ay += xv.y*kv.y; az += xv.z*kv.z; aw += xv.w*kv.w;
                    }
                }
            }
        }
        ushort4 o4;
        o4.x = f2bf(xc.x + lgb*(ax - xc.x));
        o4.y = f2bf(xc.y + lgb*(ay - xc.y));
        o4.z = f2bf(xc.z + lgb*(az - xc.z));
        o4.w = f2bf(xc.w + lgb*(aw - xc.w));
        *(ushort4*)(lmb + (size_t)n*Dd + dq*4) = o4;
    }
}

// ---- out = (lm_bf16 @ Wb + bias)*scale ; 128x128 tile, BK=64, global_load_lds + XOR swizzle ----
__global__ __launch_bounds__(256) void k_gemm_nt(const unsigned short* __restrict__ lm, const unsigned short* __restrict__ WbT,
                                                 const float* __restrict__ bias, const float* __restrict__ scalev,
                                                 float* __restrict__ out){
    __shared__ unsigned short As[128*64];   // 16 KB, [row][chunk^ (row&7)] swizzled
    __shared__ unsigned short Bs2[128*64];  // 16 KB
    int b = blockIdx.y;
    int nt = blockIdx.x / 3, ot = blockIdx.x % 3;
    int n0 = nt*128, o0 = ot*128;
    int t = threadIdx.x;
    int w = t >> 6, l = t & 63;
    int wr = w >> 1, wc = w & 1;
    const unsigned short* Ab = lm + (size_t)b*Nn*Dd;
    const unsigned short* Bt = WbT + (size_t)b*OUTo*Dd;
    int srow = l >> 3;               // 0..7 within 8-row window
    int sch  = (l & 7) ^ srow;       // inverse-swizzled source chunk
    f32x4 acc[4][4];
    #pragma unroll
    for (int fi = 0; fi < 4; ++fi)
        #pragma unroll
        for (int fj = 0; fj < 4; ++fj)
            #pragma unroll
            for (int q = 0; q < 4; ++q) acc[fi][fj][q] = 0.f;
    for (int kt = 0; kt < 6; ++kt){
        int k0 = kt*64;
        #pragma unroll
        for (int i = 0; i < 4; ++i){
            int r0 = (i*4 + w)*8;
            GLDS16(Ab + (size_t)(n0 + r0 + srow)*Dd + k0 + sch*8, &As[r0*64]);
            GLDS16(Bt + (size_t)(o0 + r0 + srow)*Dd + k0 + sch*8, &Bs2[r0*64]);
        }
        __syncthreads();
        #pragma unroll
        for (int kc = 0; kc < 2; ++kc){
            short8 a[4], bb[4];
            int ch = ((kc*4 + (l>>4)) ^ (l&7))*8;
            #pragma unroll
            for (int f = 0; f < 4; ++f){
                int ra = wr*64 + f*16 + (l&15);
                int rb2 = wc*64 + f*16 + (l&15);
                a[f]  = *(const short8*)&As [ra*64  + ch];
                bb[f] = *(const short8*)&Bs2[rb2*64 + ch];
            }
            #pragma unroll
            for (int fi = 0; fi < 4; ++fi)
                #pragma unroll
                for (int fj = 0; fj < 4; ++fj)
                    acc[fi][fj] = MFMA_BF16(a[fi], bb[fj], acc[fi][fj]);
        }
        __syncthreads();
    }
    const float* sv = scalev + (size_t)b*OUTo;
    #pragma unroll
    for (int fj = 0; fj < 4; ++fj){
        int col = o0 + wc*64 + fj*16 + (l&15);
        float svv = sv[col], bvv = bias[col];
        #pragma unroll
        for (int fi = 0; fi < 4; ++fi){
            int rowb = n0 + wr*64 + fi*16 + (l>>4)*4;
            #pragma unroll
            for (int r = 0; r < 4; ++r){
                int row = rowb + r;
                if (row < Nn)
                    out[((size_t)b*Nn + row)*OUTo + col] = svv*(bvv + acc[fi][fj][r]);
            }
        }
    }
}

extern "C" void kernel_launch(void* const* d_in, const int* in_sizes, int n_in,
                              void* d_out, int out_size, void* d_ws, size_t ws_size,
                              hipStream_t stream){
    const float* x     = (const float*)d_in[0];
    const float* Wsh   = (const float*)d_in[1];
    const float* bias  = (const float*)d_in[2];
    const float* lb    = (const float*)d_in[3];
    const float* rb    = (const float*)d_in[4];
    const float* sbasis= (const float*)d_in[5];
    const float* sstr  = (const float*)d_in[6];
    const float* kw    = (const float*)d_in[7];
    const float* w1    = (const float*)d_in[8];
    const float* b1    = (const float*)d_in[9];
    const float* w_rot = (const float*)d_in[10];
    const float* b_rot = (const float*)d_in[11];
    const float* w_rg  = (const float*)d_in[12];
    const float* b_rg  = (const float*)d_in[13];
    const float* w_lg  = (const float*)d_in[14];
    const float* b_lg  = (const float*)d_in[15];
    const float* w_sc  = (const float*)d_in[16];
    const float* b_sc  = (const float*)d_in[17];
    float* out = (float*)d_out;
    float* ws  = (float*)d_ws;

    float* ps     = ws + OFF_PSTAT;
    float* z      = ws + OFF_Z;
    float* h      = ws + OFF_H;
    float* rc     = ws + OFF_RC;
    float* rg     = ws + OFF_RG;
    float* lg     = ws + OFF_LG;
    float* sc     = ws + OFF_SC;
    float* scalev = ws + OFF_SCALE;
    float* n2     = ws + OFF_N2;
    float* P      = ws + OFF_P;
    float* Q      = ws + OFF_Q;
    float* G      = ws + OFF_G;
    float* QW     = ws + OFF_QW;
    unsigned short* Pb  = (unsigned short*)(ws + OFF_PB);
    float* Ep     = ws + OFF_EP;
    unsigned short* ZT  = (unsigned short*)(ws + OFF_ZT);
    unsigned short* WbT = (unsigned short*)(ws + OFF_WBT);
    unsigned short* lmb = (unsigned short*)(ws + OFF_LM);

    k_stats   <<<dim3(8, Bb), 384, 0, stream>>>(x, ps);
    k_statsfin<<<Bb, 384, 0, stream>>>(x, ps, z, lmb);
    k_mlp     <<<Bb, 128, 0, stream>>>(z, w1, b1, w_rot, b_rot, w_rg, b_rg, w_lg, b_lg, w_sc, b_sc,
                                       h, rc, rg, lg, sc);
    k_scalevec<<<Bb, 384, 0, stream>>>(sc, sbasis, sstr, scalev);
    k_norm    <<<Kk, 64, 0, stream>>>(lb, rb, n2);
    k_pq      <<<192, 256, 0, stream>>>(lb, rb, P, Q, Pb);
    k_gram    <<<128, 128, 0, stream>>>(P, Q, G);
    k_qw      <<<128, 384, 0, stream>>>(Q, Wsh, QW);
    k_cayley  <<<Bb, 512, 0, stream>>>(G, rc, n2, rg, Ep);
    k_zmatT   <<<dim3(32, Bb), 384, 0, stream>>>(Ep, QW, ZT);
    k_wbt     <<<dim3(36, Bb), 256, 0, stream>>>(ZT, Pb, Wsh, WbT);
    k_lm      <<<dim3(32, Bb), 384, 0, stream>>>(x, kw, lg, lmb);
    k_gemm_nt <<<dim3(27, Bb), 256, 0, stream>>>(lmb, WbT, bias, scalev, out);
}

// Round 5
// 296.743 us; speedup vs baseline: 3.5417x; 1.1953x over previous
//
#include <hip/hip_runtime.h>
#include <hip/hip_bf16.h>
#include <math.h>

// B=64 N=1025 D=384 K=8 R=8 KS=8 H=128 CIN=1152 OUT=384 ; rank m = 2*K*R = 128
static const int Bb = 64, Nn = 1025, Dd = 384, Kk = 8, Rr = 8, Hh = 128, CINc = 1152, OUTo = 384;

// ---- workspace layout (float offsets) ----
#define OFF_PSTAT 0u          // 393216
#define OFF_RC    475136u     // 512
#define OFF_RG    475648u     // 64
#define OFF_LG    475712u     // 64
#define OFF_SCALE 476288u     // 24576
#define OFF_N2    505472u     // 128
#define OFF_P     505600u     // 49152 (f32)
#define OFF_Q     554752u     // 49152 (f32)
#define OFF_G     603904u     // 16384
#define OFF_QW    620288u     // 49152 (f32)
#define OFF_PB    669440u     // 24576  (bf16 384x128)
#define OFF_EP    694016u     // 1048576
#define OFF_ZT    3839744u    // 1572864 (bf16 64x384x128)
#define OFF_WBT   5412608u    // 4718592 (bf16 64x384x384)
#define OFF_LM    10131200u   // 12595200 (bf16 64x1025x384) + 24384 float pad (127 garbage rows for GEMM tile overrun)

typedef __attribute__((ext_vector_type(8))) short short8;
typedef __attribute__((ext_vector_type(8))) __bf16 bf16x8;
typedef __attribute__((ext_vector_type(4))) float f32x4;

#define MFMA_BF16(a,b,c) __builtin_amdgcn_mfma_f32_16x16x32_bf16( \
    __builtin_bit_cast(bf16x8,(a)), __builtin_bit_cast(bf16x8,(b)), (c), 0, 0, 0)

#define GLDS16(gp, lp) __builtin_amdgcn_global_load_lds( \
    (__attribute__((address_space(1))) void*)(gp), \
    (__attribute__((address_space(3))) void*)(lp), 16, 0, 0)

__device__ __forceinline__ float gelu_t(float v){
    float u = 0.7978845608028654f*(v + 0.044715f*v*v*v);
    return 0.5f*v*(1.0f + tanhf(u));
}
__device__ __forceinline__ float sigm(float v){ return 1.0f/(1.0f+expf(-v)); }
__device__ __forceinline__ unsigned short f2bf(float v){
    return __builtin_bit_cast(unsigned short, __float2bfloat16(v));
}

// ---- per-(b,d) token stats, float4-vectorized, 8 token slices ----
__global__ __launch_bounds__(384) void k_stats(const float* __restrict__ x, float* __restrict__ ps){
    int s = blockIdx.x, b = blockIdx.y, t = threadIdx.x;
    int dq = t % 96, ng = t / 96;
    int n0 = s*129, n1 = n0+129 < Nn ? n0+129 : Nn;
    const float4* xb = (const float4*)(x + (size_t)b*Nn*Dd);
    float4 sm = make_float4(0.f,0.f,0.f,0.f), sq = make_float4(0.f,0.f,0.f,0.f);
    for (int n = n0+ng; n < n1; n += 4){
        float4 v = xb[(size_t)n*96 + dq];
        sm.x += v.x; sm.y += v.y; sm.z += v.z; sm.w += v.w;
        sq.x += v.x*v.x; sq.y += v.y*v.y; sq.z += v.z*v.z; sq.w += v.w*v.w;
    }
    __shared__ float4 smS[384];
    __shared__ float4 sqS[384];
    smS[t] = sm; sqS[t] = sq;
    __syncthreads();
    if (t < 96){
        float4 a0 = smS[t], a1 = smS[t+96], a2 = smS[t+192], a3 = smS[t+288];
        float4 q0 = sqS[t], q1 = sqS[t+96], q2 = sqS[t+192], q3 = sqS[t+288];
        float4 a = make_float4(a0.x+a1.x+a2.x+a3.x, a0.y+a1.y+a2.y+a3.y, a0.z+a1.z+a2.z+a3.z, a0.w+a1.w+a2.w+a3.w);
        float4 q = make_float4(q0.x+q1.x+q2.x+q3.x, q0.y+q1.y+q2.y+q3.y, q0.z+q1.z+q2.z+q3.z, q0.w+q1.w+q2.w+q3.w);
        ((float4*)(ps + ((size_t)(b*8+s)*2+0)*Dd))[t] = a;
        ((float4*)(ps + ((size_t)(b*8+s)*2+1)*Dd))[t] = q;
    }
}

// ---- fused: stats finalize + control MLP + heads + scalevec ; writes cls row of lm ----
__global__ __launch_bounds__(384) void k_ctrl(const float* __restrict__ x, const float* __restrict__ ps,
    const float* __restrict__ w1, const float* __restrict__ b1,
    const float* __restrict__ w_rot, const float* __restrict__ b_rot,
    const float* __restrict__ w_rg, const float* __restrict__ b_rg,
    const float* __restrict__ w_lg, const float* __restrict__ b_lg,
    const float* __restrict__ w_sc, const float* __restrict__ b_sc,
    const float* __restrict__ sbasis, const float* __restrict__ sstr,
    float* __restrict__ rc, float* __restrict__ rg, float* __restrict__ lg,
    float* __restrict__ scalev, unsigned short* __restrict__ lm){
    __shared__ float zs[1152];
    __shared__ float hp[3*128];
    __shared__ float hs[128];
    __shared__ float scl[8];
    int b = blockIdx.x, t = threadIdx.x;
    float sm = 0.f, sq = 0.f;
    for (int s = 0; s < 8; ++s){
        sm += ps[((size_t)(b*8+s)*2+0)*Dd + t];
        sq += ps[((size_t)(b*8+s)*2+1)*Dd + t];
    }
    float mean = sm*(1.0f/Nn);
    float var  = sq*(1.0f/Nn) - mean*mean;
    float cls  = x[(size_t)b*Nn*Dd + t];
    zs[t] = cls; zs[Dd + t] = mean; zs[2*Dd + t] = var;
    lm[(size_t)b*Nn*Dd + t] = f2bf(cls);
    __syncthreads();
    {   // h partials: 3 chunks of 384 per row
        int row = t & 127, part = t >> 7;
        const float* wrow = w1 + (size_t)row*CINc + part*384;
        const float* zp = zs + part*384;
        float acc = 0.f;
        for (int c = 0; c < 384; ++c) acc += zp[c]*wrow[c];
        hp[part*128 + row] = acc;
    }
    __syncthreads();
    if (t < 128)
        hs[t] = gelu_t(hp[t] + hp[128+t] + hp[256+t] + b1[t]);
    __syncthreads();
    if (t < 8){
        float acc = b_rot[t]; const float* w = w_rot + (size_t)t*Hh;
        for (int c = 0; c < Hh; ++c) acc += hs[c]*w[c];
        rc[b*8+t] = tanhf(acc);
    } else if (t == 8){
        float acc = b_rg[0];
        for (int c = 0; c < Hh; ++c) acc += hs[c]*w_rg[c];
        rg[b] = sigm(acc);
    } else if (t == 9){
        float acc = b_lg[0];
        for (int c = 0; c < Hh; ++c) acc += hs[c]*w_lg[c];
        lg[b] = sigm(acc);
    } else if (t < 18){
        int q = t-10; float acc = b_sc[q]; const float* w = w_sc + (size_t)q*Hh;
        for (int c = 0; c < Hh; ++c) acc += hs[c]*w[c];
        scl[q] = tanhf(acc);
    }
    __syncthreads();
    float acc = 0.f;
    #pragma unroll
    for (int q = 0; q < 8; ++q) acc += scl[q]*sbasis[q*OUTo + t];
    scalev[(size_t)b*OUTo + t] = 1.0f + sstr[0]*tanhf(acc);
}

// ---- ||basis_k||_F^2 = 2(tr(A B) - tr(C^2)), 8x8 grams ----
__global__ __launch_bounds__(64) void k_norm(const float* __restrict__ lb, const float* __restrict__ rb, float* __restrict__ n2){
    int k = blockIdx.x, t = threadIdx.x;
    int r = t >> 3, s = t & 7;
    const float* L = lb + (size_t)k*Dd*Rr;
    const float* R = rb + (size_t)k*Dd*Rr;
    float a = 0.f, bsum = 0.f, c = 0.f, c2 = 0.f;
    for (int d = 0; d < Dd; ++d){
        float lr = L[d*8+r], ls = L[d*8+s], rr = R[d*8+r], rs = R[d*8+s];
        a += lr*ls; bsum += rr*rs; c += lr*rs; c2 += ls*rr;
    }
    float contrib = a*bsum - c*c2;
    for (int m = 32; m > 0; m >>= 1) contrib += __shfl_xor(contrib, m, 64);
    if (t == 0) n2[k] = 2.f*contrib;
}

// ---- build P=[L|R] (f32 + bf16), Q=[R|L] ----
__global__ __launch_bounds__(256) void k_pq(const float* __restrict__ lb, const float* __restrict__ rb,
                                            float* __restrict__ P, float* __restrict__ Q, unsigned short* __restrict__ Pb){
    int idx = blockIdx.x*256 + threadIdx.x;
    int d = idx >> 7, j = idx & 127;
    int k = (j & 63) >> 3, r = j & 7;
    float lv = lb[((size_t)k*Dd + d)*Rr + r];
    float rv = rb[((size_t)k*Dd + d)*Rr + r];
    float pv = (j < 64) ? lv : rv;
    P[idx] = pv;
    Pb[idx] = f2bf(pv);
    Q[idx] = (j < 64) ? rv : lv;
}

// ---- G = Q^T P (128x128) ----
__global__ __launch_bounds__(128) void k_gram(const float* __restrict__ P, const float* __restrict__ Q, float* __restrict__ G){
    int i = blockIdx.x, j = threadIdx.x;
    float acc = 0.f;
    for (int d = 0; d < Dd; ++d) acc += Q[d*128 + i]*P[d*128 + j];
    G[i*128 + j] = acc;
}

// ---- QW = Q^T Wsh^T (128 x 384) ----
__global__ __launch_bounds__(384) void k_qw(const float* __restrict__ Q, const float* __restrict__ Wsh, float* __restrict__ QW){
    int i = blockIdx.x, o = threadIdx.x;
    float acc = 0.f;
    for (int d = 0; d < Dd; ++d) acc += Q[d*128 + i]*Wsh[(size_t)o*Dd + d];
    QW[(size_t)i*OUTo + o] = acc;
}

// ---- fused Cayley/Neumann: X = sum_{k<=2} (DG)^k B0, Ep = rg*(D + X) ----
__global__ __launch_bounds__(512) void k_cayley(const float* __restrict__ G, const float* __restrict__ rc,
                                                const float* __restrict__ n2, const float* __restrict__ rg,
                                                float* __restrict__ Ep){
    __shared__ float GT[128*128];
    __shared__ float Xs[128*128];
    int b = blockIdx.x, t = threadIdx.x;
    for (int lin = t; lin < 16384; lin += 512){
        int i = lin >> 7, m = lin & 127;
        GT[m*128 + i] = G[lin];
    }
    int j0 = (t & 15)*8, i0 = (t >> 4)*4;
    float dj[8], di[4];
    #pragma unroll
    for (int u = 0; u < 8; ++u){
        int j = j0+u; int k = (j&63)>>3;
        float nrm = fmaxf(sqrtf(n2[k]), 1e-6f);
        float al = 0.5f*rc[b*8+k]/nrm;
        dj[u] = (j < 64) ? al : -al;
    }
    #pragma unroll
    for (int u = 0; u < 4; ++u){
        int i = i0+u; int k = (i&63)>>3;
        float nrm = fmaxf(sqrtf(n2[k]), 1e-6f);
        float al = 0.5f*rc[b*8+k]/nrm;
        di[u] = (i < 64) ? al : -al;
    }
    __syncthreads();
    float B0[4][8], acc[4][8];
    #pragma unroll
    for (int ui = 0; ui < 4; ++ui)
        #pragma unroll
        for (int uj = 0; uj < 8; ++uj){
            int i = i0+ui, j = j0+uj;
            float g = GT[j*128 + i];
            B0[ui][uj] = di[ui]*g*dj[uj] + ((i==j) ? di[ui] : 0.f);
        }
    #pragma unroll
    for (int ui = 0; ui < 4; ++ui)
        #pragma unroll
        for (int uj = 0; uj < 8; ++uj)
            Xs[(i0+ui)*128 + j0+uj] = B0[ui][uj];
    __syncthreads();
    for (int pass = 0; pass < 2; ++pass){
        #pragma unroll
        for (int ui = 0; ui < 4; ++ui)
            #pragma unroll
            for (int uj = 0; uj < 8; ++uj) acc[ui][uj] = 0.f;
        for (int m = 0; m < 128; ++m){
            float4 g4 = *(const float4*)&GT[m*128 + i0];
            float4 xa = *(const float4*)&Xs[m*128 + j0];
            float4 xb = *(const float4*)&Xs[m*128 + j0 + 4];
            float gi[4] = {g4.x, g4.y, g4.z, g4.w};
            float xv[8] = {xa.x, xa.y, xa.z, xa.w, xb.x, xb.y, xb.z, xb.w};
            #pragma unroll
            for (int ui = 0; ui < 4; ++ui)
                #pragma unroll
                for (int uj = 0; uj < 8; ++uj)
                    acc[ui][uj] += gi[ui]*xv[uj];
        }
        if (pass == 0){
            __syncthreads();
            #pragma unroll
            for (int ui = 0; ui < 4; ++ui)
                #pragma unroll
                for (int uj = 0; uj < 8; ++uj)
                    Xs[(i0+ui)*128 + j0+uj] = B0[ui][uj] + di[ui]*acc[ui][uj];
            __syncthreads();
        }
    }
    float rgb = rg[b];
    #pragma unroll
    for (int ui = 0; ui < 4; ++ui){
        int i = i0+ui;
        float o[8];
        #pragma unroll
        for (int uj = 0; uj < 8; ++uj){
            int j = j0+uj;
            float x2 = B0[ui][uj] + di[ui]*acc[ui][uj];
            o[uj] = rgb*(x2 + ((i==j) ? di[ui] : 0.f));
        }
        float4* ep4 = (float4*)(Ep + ((size_t)b*128 + i)*128 + j0);
        ep4[0] = make_float4(o[0], o[1], o[2], o[3]);
        ep4[1] = make_float4(o[4], o[5], o[6], o[7]);
    }
}

// ---- ZT[b][o][m] = (Ep @ QW)^T in bf16 ----
__global__ __launch_bounds__(384) void k_zmatT(const float* __restrict__ Ep, const float* __restrict__ QW, unsigned short* __restrict__ ZT){
    __shared__ float Es[4*128];
    int ig = blockIdx.x, b = blockIdx.y, t = threadIdx.x;
    int i0 = ig*4;
    for (int lin = t; lin < 512; lin += 384)
        Es[lin] = Ep[((size_t)b*128 + i0 + (lin >> 7))*128 + (lin & 127)];
    __syncthreads();
    float a0=0.f, a1=0.f, a2=0.f, a3=0.f;
    for (int m = 0; m < 128; ++m){
        float qw = QW[(size_t)m*OUTo + t];
        a0 += Es[m]*qw; a1 += Es[128+m]*qw; a2 += Es[256+m]*qw; a3 += Es[384+m]*qw;
    }
    ushort4 uv;
    uv.x = f2bf(a0); uv.y = f2bf(a1); uv.z = f2bf(a2); uv.w = f2bf(a3);
    *(ushort4*)(ZT + ((size_t)b*OUTo + t)*128 + i0) = uv;
}

// ---- WbT[b][o][d] = Wsh[o][d] + sum_m ZT[b][o][m]*P[d][m] (MFMA NT, bf16 out) ----
__global__ __launch_bounds__(256) void k_wbt(const unsigned short* __restrict__ ZT, const unsigned short* __restrict__ Pb,
                                             const float* __restrict__ Wsh, unsigned short* __restrict__ WbT){
    __shared__ short8 As[256];
    __shared__ short8 Bs[256];
    int b = blockIdx.y;
    int mt = blockIdx.x/6, nt2 = blockIdx.x%6;
    int m0 = mt*64, n0 = nt2*64;
    int t = threadIdx.x;
    int w = t>>6, l = t&63;
    int wr = w>>1, wc = w&1;
    const unsigned short* Ab = ZT + (size_t)b*OUTo*128;
    int lrow = t>>2, lseg = t&3;
    f32x4 acc[2][2];
    #pragma unroll
    for (int mi=0;mi<2;++mi)
        #pragma unroll
        for (int ni=0;ni<2;++ni)
            #pragma unroll
            for (int q=0;q<4;++q) acc[mi][ni][q] = 0.f;
    for (int kt = 0; kt < 4; ++kt){
        int k0 = kt*32;
        short8 av = *(const short8*)(Ab + (size_t)(m0+lrow)*128 + k0 + lseg*8);
        short8 bv = *(const short8*)(Pb + (size_t)(n0+lrow)*128 + k0 + lseg*8);
        __syncthreads();
        As[lseg*64 + lrow] = av;
        Bs[lseg*64 + lrow] = bv;
        __syncthreads();
        short8 a0 = As[(l>>4)*64 + wr*32 + (l&15)];
        short8 a1 = As[(l>>4)*64 + wr*32 + 16 + (l&15)];
        short8 b0 = Bs[(l>>4)*64 + wc*32 + (l&15)];
        short8 b1 = Bs[(l>>4)*64 + wc*32 + 16 + (l&15)];
        acc[0][0] = MFMA_BF16(a0, b0, acc[0][0]);
        acc[0][1] = MFMA_BF16(a0, b1, acc[0][1]);
        acc[1][0] = MFMA_BF16(a1, b0, acc[1][0]);
        acc[1][1] = MFMA_BF16(a1, b1, acc[1][1]);
    }
    unsigned short* Wo = WbT + (size_t)b*OUTo*Dd;
    #pragma unroll
    for (int mi=0;mi<2;++mi){
        #pragma unroll
        for (int ni=0;ni<2;++ni){
            int col = n0 + wc*32 + ni*16 + (l&15);
            #pragma unroll
            for (int r=0;r<4;++r){
                int row = m0 + wr*32 + mi*16 + (l>>4)*4 + r;
                float v = Wsh[(size_t)row*Dd + col] + acc[mi][ni][r];
                Wo[(size_t)row*Dd + col] = f2bf(v);
            }
        }
    }
}

// ---- lm patches: dwconv3x3 + gate blend, float4 vec, XCD-chunked remap ----
__global__ __launch_bounds__(384) void k_lm(const float* __restrict__ x, const float* __restrict__ kw,
                                            const float* __restrict__ lg, unsigned short* __restrict__ lm){
    __shared__ float kws[9*384];
    int flat = blockIdx.x;                   // 2048
    int work = (flat & 7)*256 + (flat >> 3); // XCD-chunked: 8 batches/XCD contiguous
    int b = work >> 5, gy = work & 31;
    int t = threadIdx.x;
    for (int i = t; i < 3456; i += 384){
        int d = i % 384, tap = i / 384;
        kws[tap*384 + d] = kw[d*9 + tap];
    }
    __syncthreads();
    int dq = t % 96, gxg = t / 96;
    float lgb = lg[b];
    const float4* xb = (const float4*)(x + (size_t)b*Nn*Dd);
    unsigned short* lmb = lm + (size_t)b*Nn*Dd;
    #pragma unroll
    for (int u = 0; u < 8; ++u){
        int gx = gxg + 4*u;
        int n = 1 + (gy << 5) + gx;
        float4 xc = xb[(size_t)n*96 + dq];
        float ax = 0.f, ay = 0.f, az = 0.f, aw = 0.f;
        #pragma unroll
        for (int ky = 0; ky < 3; ++ky){
            int yy = gy + ky - 1;
            if ((unsigned)yy < 32u){
                #pragma unroll
                for (int kx = 0; kx < 3; ++kx){
                    int xx = gx + kx - 1;
                    if ((unsigned)xx < 32u){
                        float4 xv = xb[(size_t)(1 + (yy << 5) + xx)*96 + dq];
                        const float4 kv = *(const float4*)(&kws[(ky*3+kx)*384 + dq*4]);
                        ax += xv.x*kv.x; ay += xv.y*kv.y; az += xv.z*kv.z; aw += xv.w*kv.w;
                    }
                }
            }
        }
        ushort4 o4;
        o4.x = f2bf(xc.x + lgb*(ax - xc.x));
        o4.y = f2bf(xc.y + lgb*(ay - xc.y));
        o4.z = f2bf(xc.z + lgb*(az - xc.z));
        o4.w = f2bf(xc.w + lgb*(aw - xc.w));
        *(ushort4*)(lmb + (size_t)n*Dd + dq*4) = o4;
    }
}

// ---- out = (lm_bf16 @ Wb + bias)*scale ; 64x64 tile BK=64, global_load_lds + swizzle + XCD remap ----
__global__ __launch_bounds__(256) void k_gemm_nt(const unsigned short* __restrict__ lm, const unsigned short* __restrict__ WbT,
                                                 const float* __restrict__ bias, const float* __restrict__ scalev,
                                                 float* __restrict__ out){
    __shared__ unsigned short As[64*64];    // 8 KB, [row][ch ^ (row&7)]
    __shared__ unsigned short Bs2[64*64];   // 8 KB
    int flat = blockIdx.x;                      // 6528 = 64 b * 17 nt * 6 ot
    int work = (flat & 7)*816 + (flat >> 3);    // XCD-chunked: 8 batches/XCD
    int b = work / 102;
    int r = work - b*102;
    int nt = r / 6, ot = r - nt*6;
    int n0 = nt*64, o0 = ot*64;
    int t = threadIdx.x;
    int w = t >> 6, l = t & 63;
    int wr = w >> 1, wc = w & 1;
    const unsigned short* Ab = lm + (size_t)b*Nn*Dd;
    const unsigned short* Bt = WbT + (size_t)b*OUTo*Dd;
    int srow = l >> 3;
    int sch  = (l & 7) ^ srow;
    f32x4 acc[2][2];
    #pragma unroll
    for (int fi = 0; fi < 2; ++fi)
        #pragma unroll
        for (int fj = 0; fj < 2; ++fj)
            #pragma unroll
            for (int q = 0; q < 4; ++q) acc[fi][fj][q] = 0.f;
    for (int kt = 0; kt < 6; ++kt){
        int k0 = kt*64;
        #pragma unroll
        for (int i = 0; i < 2; ++i){
            int r0 = (i*4 + w)*8;   // 8 rows per GLDS16, 2 instr x 4 waves = 64 rows
            GLDS16(Ab + (size_t)(n0 + r0 + srow)*Dd + k0 + sch*8, &As[r0*64]);
            GLDS16(Bt + (size_t)(o0 + r0 + srow)*Dd + k0 + sch*8, &Bs2[r0*64]);
        }
        __syncthreads();
        #pragma unroll
        for (int kc = 0; kc < 2; ++kc){
            short8 a[2], bb[2];
            #pragma unroll
            for (int f = 0; f < 2; ++f){
                int ra  = wr*32 + f*16 + (l&15);
                int rb2 = wc*32 + f*16 + (l&15);
                int ch = (kc*4 + (l>>4)) ^ (l&7);
                a[f]  = *(const short8*)&As [ra*64  + ch*8];
                bb[f] = *(const short8*)&Bs2[rb2*64 + ch*8];
            }
            acc[0][0] = MFMA_BF16(a[0], bb[0], acc[0][0]);
            acc[0][1] = MFMA_BF16(a[0], bb[1], acc[0][1]);
            acc[1][0] = MFMA_BF16(a[1], bb[0], acc[1][0]);
            acc[1][1] = MFMA_BF16(a[1], bb[1], acc[1][1]);
        }
        __syncthreads();
    }
    const float* sv = scalev + (size_t)b*OUTo;
    #pragma unroll
    for (int fj = 0; fj < 2; ++fj){
        int col = o0 + wc*32 + fj*16 + (l&15);
        float svv = sv[col], bvv = bias[col];
        #pragma unroll
        for (int fi = 0; fi < 2; ++fi){
            int rowb = n0 + wr*32 + fi*16 + (l>>4)*4;
            #pragma unroll
            for (int rq = 0; rq < 4; ++rq){
                int row = rowb + rq;
                if (row < Nn)
                    out[((size_t)b*Nn + row)*OUTo + col] = svv*(bvv + acc[fi][fj][rq]);
            }
        }
    }
}

extern "C" void kernel_launch(void* const* d_in, const int* in_sizes, int n_in,
                              void* d_out, int out_size, void* d_ws, size_t ws_size,
                              hipStream_t stream){
    const float* x     = (const float*)d_in[0];
    const float* Wsh   = (const float*)d_in[1];
    const float* bias  = (const float*)d_in[2];
    const float* lb    = (const float*)d_in[3];
    const float* rb    = (const float*)d_in[4];
    const float* sbasis= (const float*)d_in[5];
    const float* sstr  = (const float*)d_in[6];
    const float* kw    = (const float*)d_in[7];
    const float* w1    = (const float*)d_in[8];
    const float* b1    = (const float*)d_in[9];
    const float* w_rot = (const float*)d_in[10];
    const float* b_rot = (const float*)d_in[11];
    const float* w_rg  = (const float*)d_in[12];
    const float* b_rg  = (const float*)d_in[13];
    const float* w_lg  = (const float*)d_in[14];
    const float* b_lg  = (const float*)d_in[15];
    const float* w_sc  = (const float*)d_in[16];
    const float* b_sc  = (const float*)d_in[17];
    float* out = (float*)d_out;
    float* ws  = (float*)d_ws;

    float* ps     = ws + OFF_PSTAT;
    float* rc     = ws + OFF_RC;
    float* rg     = ws + OFF_RG;
    float* lg     = ws + OFF_LG;
    float* scalev = ws + OFF_SCALE;
    float* n2     = ws + OFF_N2;
    float* P      = ws + OFF_P;
    float* Q      = ws + OFF_Q;
    float* G      = ws + OFF_G;
    float* QW     = ws + OFF_QW;
    unsigned short* Pb  = (unsigned short*)(ws + OFF_PB);
    float* Ep     = ws + OFF_EP;
    unsigned short* ZT  = (unsigned short*)(ws + OFF_ZT);
    unsigned short* WbT = (unsigned short*)(ws + OFF_WBT);
    unsigned short* lmb = (unsigned short*)(ws + OFF_LM);

    k_stats   <<<dim3(8, Bb), 384, 0, stream>>>(x, ps);
    k_ctrl    <<<Bb, 384, 0, stream>>>(x, ps, w1, b1, w_rot, b_rot, w_rg, b_rg, w_lg, b_lg,
                                       w_sc, b_sc, sbasis, sstr, rc, rg, lg, scalev, lmb);
    k_norm    <<<Kk, 64, 0, stream>>>(lb, rb, n2);
    k_pq      <<<192, 256, 0, stream>>>(lb, rb, P, Q, Pb);
    k_gram    <<<128, 128, 0, stream>>>(P, Q, G);
    k_qw      <<<128, 384, 0, stream>>>(Q, Wsh, QW);
    k_cayley  <<<Bb, 512, 0, stream>>>(G, rc, n2, rg, Ep);
    k_zmatT   <<<dim3(32, Bb), 384, 0, stream>>>(Ep, QW, ZT);
    k_wbt     <<<dim3(36, Bb), 256, 0, stream>>>(ZT, Pb, Wsh, WbT);
    k_lm      <<<2048, 384, 0, stream>>>(x, kw, lg, lmb);
    k_gemm_nt <<<6528, 256, 0, stream>>>(lmb, WbT, bias, scalev, out);
}

// Round 6
// 254.632 us; speedup vs baseline: 4.1274x; 1.1654x over previous
//
#include <hip/hip_runtime.h>
#include <hip/hip_bf16.h>
#include <math.h>

// B=64 N=1025 D=384 K=8 R=8 KS=8 H=128 CIN=1152 OUT=384 ; rank m = 2*K*R = 128
static const int Bb = 64, Nn = 1025, Dd = 384, Kk = 8, Rr = 8, Hh = 128, CINc = 1152, OUTo = 384;

// ---- workspace layout (float offsets) ----
#define OFF_PSTAT 0u          // 393216
#define OFF_RC    475136u     // 512
#define OFF_RG    475648u     // 64
#define OFF_LG    475712u     // 64
#define OFF_SCALE 476288u     // 24576
#define OFF_N2    505472u     // 128
#define OFF_P     505600u     // 49152 (f32)
#define OFF_Q     554752u     // 49152 (f32)
#define OFF_G     603904u     // 16384
#define OFF_QW    620288u     // 49152 (f32)
#define OFF_PB    669440u     // 24576  (bf16 384x128)
#define OFF_EP    694016u     // 1048576
#define OFF_ZT    3839744u    // 1572864 (bf16 64x384x128)
#define OFF_WBT   5412608u    // 4718592 (bf16 64x384x384)
#define OFF_LM    10131200u   // 12595200 (bf16 64x1025x384) + 24384 float pad (127 garbage rows for GEMM tile overrun)

typedef __attribute__((ext_vector_type(8))) short short8;
typedef __attribute__((ext_vector_type(8))) __bf16 bf16x8;
typedef __attribute__((ext_vector_type(4))) float f32x4;

#define MFMA_BF16(a,b,c) __builtin_amdgcn_mfma_f32_16x16x32_bf16( \
    __builtin_bit_cast(bf16x8,(a)), __builtin_bit_cast(bf16x8,(b)), (c), 0, 0, 0)

#define GLDS16(gp, lp) __builtin_amdgcn_global_load_lds( \
    (__attribute__((address_space(1))) void*)(gp), \
    (__attribute__((address_space(3))) void*)(lp), 16, 0, 0)

__device__ __forceinline__ float gelu_t(float v){
    float u = 0.7978845608028654f*(v + 0.044715f*v*v*v);
    return 0.5f*v*(1.0f + tanhf(u));
}
__device__ __forceinline__ float sigm(float v){ return 1.0f/(1.0f+expf(-v)); }
__device__ __forceinline__ unsigned short f2bf(float v){
    return __builtin_bit_cast(unsigned short, __float2bfloat16(v));
}

// ---- per-(b,d) token stats, float4-vectorized, 8 token slices ----
__global__ __launch_bounds__(384) void k_stats(const float* __restrict__ x, float* __restrict__ ps){
    int s = blockIdx.x, b = blockIdx.y, t = threadIdx.x;
    int dq = t % 96, ng = t / 96;
    int n0 = s*129, n1 = n0+129 < Nn ? n0+129 : Nn;
    const float4* xb = (const float4*)(x + (size_t)b*Nn*Dd);
    float4 sm = make_float4(0.f,0.f,0.f,0.f), sq = make_float4(0.f,0.f,0.f,0.f);
    for (int n = n0+ng; n < n1; n += 4){
        float4 v = xb[(size_t)n*96 + dq];
        sm.x += v.x; sm.y += v.y; sm.z += v.z; sm.w += v.w;
        sq.x += v.x*v.x; sq.y += v.y*v.y; sq.z += v.z*v.z; sq.w += v.w*v.w;
    }
    __shared__ float4 smS[384];
    __shared__ float4 sqS[384];
    smS[t] = sm; sqS[t] = sq;
    __syncthreads();
    if (t < 96){
        float4 a0 = smS[t], a1 = smS[t+96], a2 = smS[t+192], a3 = smS[t+288];
        float4 q0 = sqS[t], q1 = sqS[t+96], q2 = sqS[t+192], q3 = sqS[t+288];
        float4 a = make_float4(a0.x+a1.x+a2.x+a3.x, a0.y+a1.y+a2.y+a3.y, a0.z+a1.z+a2.z+a3.z, a0.w+a1.w+a2.w+a3.w);
        float4 q = make_float4(q0.x+q1.x+q2.x+q3.x, q0.y+q1.y+q2.y+q3.y, q0.z+q1.z+q2.z+q3.z, q0.w+q1.w+q2.w+q3.w);
        ((float4*)(ps + ((size_t)(b*8+s)*2+0)*Dd))[t] = a;
        ((float4*)(ps + ((size_t)(b*8+s)*2+1)*Dd))[t] = q;
    }
}

// ---- fused: stats finalize + control MLP + heads + scalevec ; writes cls row of lm ----
__global__ __launch_bounds__(384) void k_ctrl(const float* __restrict__ x, const float* __restrict__ ps,
    const float* __restrict__ w1, const float* __restrict__ b1,
    const float* __restrict__ w_rot, const float* __restrict__ b_rot,
    const float* __restrict__ w_rg, const float* __restrict__ b_rg,
    const float* __restrict__ w_lg, const float* __restrict__ b_lg,
    const float* __restrict__ w_sc, const float* __restrict__ b_sc,
    const float* __restrict__ sbasis, const float* __restrict__ sstr,
    float* __restrict__ rc, float* __restrict__ rg, float* __restrict__ lg,
    float* __restrict__ scalev, unsigned short* __restrict__ lm){
    __shared__ float zs[1152];
    __shared__ float hp[3*128];
    __shared__ float hs[128];
    __shared__ float scl[8];
    int b = blockIdx.x, t = threadIdx.x;
    float sm = 0.f, sq = 0.f;
    for (int s = 0; s < 8; ++s){
        sm += ps[((size_t)(b*8+s)*2+0)*Dd + t];
        sq += ps[((size_t)(b*8+s)*2+1)*Dd + t];
    }
    float mean = sm*(1.0f/Nn);
    float var  = sq*(1.0f/Nn) - mean*mean;
    float cls  = x[(size_t)b*Nn*Dd + t];
    zs[t] = cls; zs[Dd + t] = mean; zs[2*Dd + t] = var;
    lm[(size_t)b*Nn*Dd + t] = f2bf(cls);
    __syncthreads();
    {
        int row = t & 127, part = t >> 7;
        const float* wrow = w1 + (size_t)row*CINc + part*384;
        const float* zp = zs + part*384;
        float acc = 0.f;
        for (int c = 0; c < 384; ++c) acc += zp[c]*wrow[c];
        hp[part*128 + row] = acc;
    }
    __syncthreads();
    if (t < 128)
        hs[t] = gelu_t(hp[t] + hp[128+t] + hp[256+t] + b1[t]);
    __syncthreads();
    if (t < 8){
        float acc = b_rot[t]; const float* w = w_rot + (size_t)t*Hh;
        for (int c = 0; c < Hh; ++c) acc += hs[c]*w[c];
        rc[b*8+t] = tanhf(acc);
    } else if (t == 8){
        float acc = b_rg[0];
        for (int c = 0; c < Hh; ++c) acc += hs[c]*w_rg[c];
        rg[b] = sigm(acc);
    } else if (t == 9){
        float acc = b_lg[0];
        for (int c = 0; c < Hh; ++c) acc += hs[c]*w_lg[c];
        lg[b] = sigm(acc);
    } else if (t < 18){
        int q = t-10; float acc = b_sc[q]; const float* w = w_sc + (size_t)q*Hh;
        for (int c = 0; c < Hh; ++c) acc += hs[c]*w[c];
        scl[q] = tanhf(acc);
    }
    __syncthreads();
    float acc = 0.f;
    #pragma unroll
    for (int q = 0; q < 8; ++q) acc += scl[q]*sbasis[q*OUTo + t];
    scalev[(size_t)b*OUTo + t] = 1.0f + sstr[0]*tanhf(acc);
}

// ---- merged: blocks 0..7 = ||basis_k||^2 via 8x8 grams; blocks 8..199 = P/Q build ----
__global__ __launch_bounds__(256) void k_prep(const float* __restrict__ lb, const float* __restrict__ rb,
                                              float* __restrict__ n2, float* __restrict__ P,
                                              float* __restrict__ Q, unsigned short* __restrict__ Pb){
    int bid = blockIdx.x, t = threadIdx.x;
    if (bid < 8){
        if (t < 64){
            int k = bid;
            int r = t >> 3, s = t & 7;
            const float* L = lb + (size_t)k*Dd*Rr;
            const float* R = rb + (size_t)k*Dd*Rr;
            float a = 0.f, bsum = 0.f, c = 0.f, c2 = 0.f;
            for (int d = 0; d < Dd; ++d){
                float lr = L[d*8+r], ls = L[d*8+s], rr = R[d*8+r], rs = R[d*8+s];
                a += lr*ls; bsum += rr*rs; c += lr*rs; c2 += ls*rr;
            }
            float contrib = a*bsum - c*c2;
            for (int m = 32; m > 0; m >>= 1) contrib += __shfl_xor(contrib, m, 64);
            if (t == 0) n2[k] = 2.f*contrib;
        }
    } else {
        int idx = (bid-8)*256 + t;
        int d = idx >> 7, j = idx & 127;
        int k = (j & 63) >> 3, r = j & 7;
        float lv = lb[((size_t)k*Dd + d)*Rr + r];
        float rv = rb[((size_t)k*Dd + d)*Rr + r];
        float pv = (j < 64) ? lv : rv;
        P[idx] = pv;
        Pb[idx] = f2bf(pv);
        Q[idx] = (j < 64) ? rv : lv;
    }
}

// ---- merged: G[i][*] = Q^T P row i ; QW[i][*] = Q^T Wsh^T row i ----
__global__ __launch_bounds__(512) void k_gramqw(const float* __restrict__ P, const float* __restrict__ Q,
                                                const float* __restrict__ Wsh,
                                                float* __restrict__ G, float* __restrict__ QW){
    __shared__ float qc[384];
    int i = blockIdx.x, t = threadIdx.x;
    for (int d = t; d < Dd; d += 512) qc[d] = Q[d*128 + i];
    __syncthreads();
    if (t < 128){
        float a = 0.f;
        for (int d = 0; d < Dd; ++d) a += qc[d]*P[d*128 + t];
        G[i*128 + t] = a;
    } else {
        int o = t - 128;
        float a = 0.f;
        const float* wrow = Wsh + (size_t)o*Dd;
        for (int d = 0; d < Dd; ++d) a += qc[d]*wrow[d];
        QW[(size_t)i*OUTo + o] = a;
    }
}

// ---- fused Cayley/Neumann: X = sum_{k<=2} (DG)^k B0, Ep = rg*(D + X) ----
__global__ __launch_bounds__(512) void k_cayley(const float* __restrict__ G, const float* __restrict__ rc,
                                                const float* __restrict__ n2, const float* __restrict__ rg,
                                                float* __restrict__ Ep){
    __shared__ float GT[128*128];
    __shared__ float Xs[128*128];
    int b = blockIdx.x, t = threadIdx.x;
    for (int lin = t; lin < 16384; lin += 512){
        int i = lin >> 7, m = lin & 127;
        GT[m*128 + i] = G[lin];
    }
    int j0 = (t & 15)*8, i0 = (t >> 4)*4;
    float dj[8], di[4];
    #pragma unroll
    for (int u = 0; u < 8; ++u){
        int j = j0+u; int k = (j&63)>>3;
        float nrm = fmaxf(sqrtf(n2[k]), 1e-6f);
        float al = 0.5f*rc[b*8+k]/nrm;
        dj[u] = (j < 64) ? al : -al;
    }
    #pragma unroll
    for (int u = 0; u < 4; ++u){
        int i = i0+u; int k = (i&63)>>3;
        float nrm = fmaxf(sqrtf(n2[k]), 1e-6f);
        float al = 0.5f*rc[b*8+k]/nrm;
        di[u] = (i < 64) ? al : -al;
    }
    __syncthreads();
    float B0[4][8], acc[4][8];
    #pragma unroll
    for (int ui = 0; ui < 4; ++ui)
        #pragma unroll
        for (int uj = 0; uj < 8; ++uj){
            int i = i0+ui, j = j0+uj;
            float g = GT[j*128 + i];
            B0[ui][uj] = di[ui]*g*dj[uj] + ((i==j) ? di[ui] : 0.f);
        }
    #pragma unroll
    for (int ui = 0; ui < 4; ++ui)
        #pragma unroll
        for (int uj = 0; uj < 8; ++uj)
            Xs[(i0+ui)*128 + j0+uj] = B0[ui][uj];
    __syncthreads();
    for (int pass = 0; pass < 2; ++pass){
        #pragma unroll
        for (int ui = 0; ui < 4; ++ui)
            #pragma unroll
            for (int uj = 0; uj < 8; ++uj) acc[ui][uj] = 0.f;
        for (int m = 0; m < 128; ++m){
            float4 g4 = *(const float4*)&GT[m*128 + i0];
            float4 xa = *(const float4*)&Xs[m*128 + j0];
            float4 xb = *(const float4*)&Xs[m*128 + j0 + 4];
            float gi[4] = {g4.x, g4.y, g4.z, g4.w};
            float xv[8] = {xa.x, xa.y, xa.z, xa.w, xb.x, xb.y, xb.z, xb.w};
            #pragma unroll
            for (int ui = 0; ui < 4; ++ui)
                #pragma unroll
                for (int uj = 0; uj < 8; ++uj)
                    acc[ui][uj] += gi[ui]*xv[uj];
        }
        if (pass == 0){
            __syncthreads();
            #pragma unroll
            for (int ui = 0; ui < 4; ++ui)
                #pragma unroll
                for (int uj = 0; uj < 8; ++uj)
                    Xs[(i0+ui)*128 + j0+uj] = B0[ui][uj] + di[ui]*acc[ui][uj];
            __syncthreads();
        }
    }
    float rgb = rg[b];
    #pragma unroll
    for (int ui = 0; ui < 4; ++ui){
        int i = i0+ui;
        float o[8];
        #pragma unroll
        for (int uj = 0; uj < 8; ++uj){
            int j = j0+uj;
            float x2 = B0[ui][uj] + di[ui]*acc[ui][uj];
            o[uj] = rgb*(x2 + ((i==j) ? di[ui] : 0.f));
        }
        float4* ep4 = (float4*)(Ep + ((size_t)b*128 + i)*128 + j0);
        ep4[0] = make_float4(o[0], o[1], o[2], o[3]);
        ep4[1] = make_float4(o[4], o[5], o[6], o[7]);
    }
}

// ---- ZT[b][o][m] = (Ep @ QW)^T in bf16 ----
__global__ __launch_bounds__(384) void k_zmatT(const float* __restrict__ Ep, const float* __restrict__ QW, unsigned short* __restrict__ ZT){
    __shared__ float Es[4*128];
    int ig = blockIdx.x, b = blockIdx.y, t = threadIdx.x;
    int i0 = ig*4;
    for (int lin = t; lin < 512; lin += 384)
        Es[lin] = Ep[((size_t)b*128 + i0 + (lin >> 7))*128 + (lin & 127)];
    __syncthreads();
    float a0=0.f, a1=0.f, a2=0.f, a3=0.f;
    for (int m = 0; m < 128; ++m){
        float qw = QW[(size_t)m*OUTo + t];
        a0 += Es[m]*qw; a1 += Es[128+m]*qw; a2 += Es[256+m]*qw; a3 += Es[384+m]*qw;
    }
    ushort4 uv;
    uv.x = f2bf(a0); uv.y = f2bf(a1); uv.z = f2bf(a2); uv.w = f2bf(a3);
    *(ushort4*)(ZT + ((size_t)b*OUTo + t)*128 + i0) = uv;
}

// ---- WbT[b][o][d] = Wsh[o][d] + sum_m ZT[b][o][m]*P[d][m] (MFMA NT, bf16 out) ----
__global__ __launch_bounds__(256) void k_wbt(const unsigned short* __restrict__ ZT, const unsigned short* __restrict__ Pb,
                                             const float* __restrict__ Wsh, unsigned short* __restrict__ WbT){
    __shared__ short8 As[256];
    __shared__ short8 Bs[256];
    int b = blockIdx.y;
    int mt = blockIdx.x/6, nt2 = blockIdx.x%6;
    int m0 = mt*64, n0 = nt2*64;
    int t = threadIdx.x;
    int w = t>>6, l = t&63;
    int wr = w>>1, wc = w&1;
    const unsigned short* Ab = ZT + (size_t)b*OUTo*128;
    int lrow = t>>2, lseg = t&3;
    f32x4 acc[2][2];
    #pragma unroll
    for (int mi=0;mi<2;++mi)
        #pragma unroll
        for (int ni=0;ni<2;++ni)
            #pragma unroll
            for (int q=0;q<4;++q) acc[mi][ni][q] = 0.f;
    for (int kt = 0; kt < 4; ++kt){
        int k0 = kt*32;
        short8 av = *(const short8*)(Ab + (size_t)(m0+lrow)*128 + k0 + lseg*8);
        short8 bv = *(const short8*)(Pb + (size_t)(n0+lrow)*128 + k0 + lseg*8);
        __syncthreads();
        As[lseg*64 + lrow] = av;
        Bs[lseg*64 + lrow] = bv;
        __syncthreads();
        short8 a0 = As[(l>>4)*64 + wr*32 + (l&15)];
        short8 a1 = As[(l>>4)*64 + wr*32 + 16 + (l&15)];
        short8 b0 = Bs[(l>>4)*64 + wc*32 + (l&15)];
        short8 b1 = Bs[(l>>4)*64 + wc*32 + 16 + (l&15)];
        acc[0][0] = MFMA_BF16(a0, b0, acc[0][0]);
        acc[0][1] = MFMA_BF16(a0, b1, acc[0][1]);
        acc[1][0] = MFMA_BF16(a1, b0, acc[1][0]);
        acc[1][1] = MFMA_BF16(a1, b1, acc[1][1]);
    }
    unsigned short* Wo = WbT + (size_t)b*OUTo*Dd;
    #pragma unroll
    for (int mi=0;mi<2;++mi){
        #pragma unroll
        for (int ni=0;ni<2;++ni){
            int col = n0 + wc*32 + ni*16 + (l&15);
            #pragma unroll
            for (int r=0;r<4;++r){
                int row = m0 + wr*32 + mi*16 + (l>>4)*4 + r;
                float v = Wsh[(size_t)row*Dd + col] + acc[mi][ni][r];
                Wo[(size_t)row*Dd + col] = f2bf(v);
            }
        }
    }
}

// ---- lm patches: dwconv3x3 + gate blend, float4 vec, XCD-chunked remap ----
__global__ __launch_bounds__(384) void k_lm(const float* __restrict__ x, const float* __restrict__ kw,
                                            const float* __restrict__ lg, unsigned short* __restrict__ lm){
    __shared__ float kws[9*384];
    int flat = blockIdx.x;
    int work = (flat & 7)*256 + (flat >> 3);
    int b = work >> 5, gy = work & 31;
    int t = threadIdx.x;
    for (int i = t; i < 3456; i += 384){
        int d = i % 384, tap = i / 384;
        kws[tap*384 + d] = kw[d*9 + tap];
    }
    __syncthreads();
    int dq = t % 96, gxg = t / 96;
    float lgb = lg[b];
    const float4* xb = (const float4*)(x + (size_t)b*Nn*Dd);
    unsigned short* lmb = lm + (size_t)b*Nn*Dd;
    #pragma unroll
    for (int u = 0; u < 8; ++u){
        int gx = gxg + 4*u;
        int n = 1 + (gy << 5) + gx;
        float4 xc = xb[(size_t)n*96 + dq];
        float ax = 0.f, ay = 0.f, az = 0.f, aw = 0.f;
        #pragma unroll
        for (int ky = 0; ky < 3; ++ky){
            int yy = gy + ky - 1;
            if ((unsigned)yy < 32u){
                #pragma unroll
                for (int kx = 0; kx < 3; ++kx){
                    int xx = gx + kx - 1;
                    if ((unsigned)xx < 32u){
                        float4 xv = xb[(size_t)(1 + (yy << 5) + xx)*96 + dq];
                        const float4 kv = *(const float4*)(&kws[(ky*3+kx)*384 + dq*4]);
                        ax += xv.x*kv.x; ay += xv.y*kv.y; az += xv.z*kv.z; aw += xv.w*kv.w;
                    }
                }
            }
        }
        ushort4 o4;
        o4.x = f2bf(xc.x + lgb*(ax - xc.x));
        o4.y = f2bf(xc.y + lgb*(ay - xc.y));
        o4.z = f2bf(xc.z + lgb*(az - xc.z));
        o4.w = f2bf(xc.w + lgb*(aw - xc.w));
        *(ushort4*)(lmb + (size_t)n*Dd + dq*4) = o4;
    }
}

// ---- out = (lm_bf16 @ Wb + bias)*scale ; 64x64 tile BK=64, double-buffered T3-min pipeline,
//      global_load_lds + XOR swizzle + XCD remap + float4 epilogue via LDS transpose ----
__global__ __launch_bounds__(256) void k_gemm_nt(const unsigned short* __restrict__ lm, const unsigned short* __restrict__ WbT,
                                                 const float* __restrict__ bias, const float* __restrict__ scalev,
                                                 float* __restrict__ out){
    __shared__ unsigned short smem[16384];   // 32 KB: [buf][A 4096 | B 4096]
    __shared__ float svs[64];
    __shared__ float bvs[64];
    int flat = blockIdx.x;                      // 6528 = 64 b * 17 nt * 6 ot
    int work = (flat & 7)*816 + (flat >> 3);    // XCD-chunked
    int b = work / 102;
    int r = work - b*102;
    int nt = r / 6, ot = r - nt*6;
    int n0 = nt*64, o0 = ot*64;
    int t = threadIdx.x;
    int w = t >> 6, l = t & 63;
    int wr = w >> 1, wc = w & 1;
    const unsigned short* Ab = lm + (size_t)b*Nn*Dd;
    const unsigned short* Bt = WbT + (size_t)b*OUTo*Dd;
    if (t < 64){ svs[t] = scalev[(size_t)b*OUTo + o0 + t]; bvs[t] = bias[o0 + t]; }
    int srow = l >> 3;
    int sch  = (l & 7) ^ srow;
    f32x4 acc[2][2];
    #pragma unroll
    for (int fi = 0; fi < 2; ++fi)
        #pragma unroll
        for (int fj = 0; fj < 2; ++fj)
            #pragma unroll
            for (int q = 0; q < 4; ++q) acc[fi][fj][q] = 0.f;

#define STAGE(bufi, k0) { \
    unsigned short* Adst = &smem[(bufi)*8192]; \
    unsigned short* Bdst = &smem[(bufi)*8192 + 4096]; \
    _Pragma("unroll") \
    for (int i = 0; i < 2; ++i){ \
        int r0 = (i*4 + w)*8; \
        GLDS16(Ab + (size_t)(n0 + r0 + srow)*Dd + (k0) + sch*8, Adst + r0*64); \
        GLDS16(Bt + (size_t)(o0 + r0 + srow)*Dd + (k0) + sch*8, Bdst + r0*64); \
    } }

    STAGE(0, 0);
    __syncthreads();
    int cur = 0;
    for (int kt = 0; kt < 6; ++kt){
        if (kt < 5) STAGE(cur^1, (kt+1)*64);
        const unsigned short* As  = &smem[cur*8192];
        const unsigned short* Bs2 = &smem[cur*8192 + 4096];
        #pragma unroll
        for (int kc = 0; kc < 2; ++kc){
            short8 a[2], bb[2];
            int ch = (kc*4 + (l>>4)) ^ (l&7);
            #pragma unroll
            for (int f = 0; f < 2; ++f){
                int ra  = wr*32 + f*16 + (l&15);
                int rb2 = wc*32 + f*16 + (l&15);
                a[f]  = *(const short8*)&As [ra*64  + ch*8];
                bb[f] = *(const short8*)&Bs2[rb2*64 + ch*8];
            }
            acc[0][0] = MFMA_BF16(a[0], bb[0], acc[0][0]);
            acc[0][1] = MFMA_BF16(a[0], bb[1], acc[0][1]);
            acc[1][0] = MFMA_BF16(a[1], bb[0], acc[1][0]);
            acc[1][1] = MFMA_BF16(a[1], bb[1], acc[1][1]);
        }
        __syncthreads();     // vmcnt(0)+lgkmcnt(0)+barrier: next-tile loads landed, all reads done
        cur ^= 1;
    }
#undef STAGE
    // epilogue: stage acc in LDS (aliases dead staging bufs), read back row-major, float4 stores
    float* Cs = (float*)smem;            // [64][68] = 17.4 KB <= 32 KB
    #pragma unroll
    for (int fi = 0; fi < 2; ++fi)
        #pragma unroll
        for (int fj = 0; fj < 2; ++fj){
            int col = wc*32 + fj*16 + (l&15);
            #pragma unroll
            for (int q = 0; q < 4; ++q){
                int row = wr*32 + fi*16 + (l>>4)*4 + q;
                Cs[row*68 + col] = acc[fi][fj][q];
            }
        }
    __syncthreads();
    #pragma unroll
    for (int p = 0; p < 4; ++p){
        int idx = p*256 + t;             // 0..1023 = 64 rows x 16 float4
        int row = idx >> 4, c4 = idx & 15;
        int gr = n0 + row;
        if (gr < Nn){
            float4 v = *(const float4*)&Cs[row*68 + c4*4];
            float4 o4;
            o4.x = svs[c4*4+0]*(bvs[c4*4+0] + v.x);
            o4.y = svs[c4*4+1]*(bvs[c4*4+1] + v.y);
            o4.z = svs[c4*4+2]*(bvs[c4*4+2] + v.z);
            o4.w = svs[c4*4+3]*(bvs[c4*4+3] + v.w);
            *(float4*)(out + ((size_t)b*Nn + gr)*OUTo + o0 + c4*4) = o4;
        }
    }
}

extern "C" void kernel_launch(void* const* d_in, const int* in_sizes, int n_in,
                              void* d_out, int out_size, void* d_ws, size_t ws_size,
                              hipStream_t stream){
    const float* x     = (const float*)d_in[0];
    const float* Wsh   = (const float*)d_in[1];
    const float* bias  = (const float*)d_in[2];
    const float* lb    = (const float*)d_in[3];
    const float* rb    = (const float*)d_in[4];
    const float* sbasis= (const float*)d_in[5];
    const float* sstr  = (const float*)d_in[6];
    const float* kw    = (const float*)d_in[7];
    const float* w1    = (const float*)d_in[8];
    const float* b1    = (const float*)d_in[9];
    const float* w_rot = (const float*)d_in[10];
    const float* b_rot = (const float*)d_in[11];
    const float* w_rg  = (const float*)d_in[12];
    const float* b_rg  = (const float*)d_in[13];
    const float* w_lg  = (const float*)d_in[14];
    const float* b_lg  = (const float*)d_in[15];
    const float* w_sc  = (const float*)d_in[16];
    const float* b_sc  = (const float*)d_in[17];
    float* out = (float*)d_out;
    float* ws  = (float*)d_ws;

    float* ps     = ws + OFF_PSTAT;
    float* rc     = ws + OFF_RC;
    float* rg     = ws + OFF_RG;
    float* lg     = ws + OFF_LG;
    float* scalev = ws + OFF_SCALE;
    float* n2     = ws + OFF_N2;
    float* P      = ws + OFF_P;
    float* Q      = ws + OFF_Q;
    float* G      = ws + OFF_G;
    float* QW     = ws + OFF_QW;
    unsigned short* Pb  = (unsigned short*)(ws + OFF_PB);
    float* Ep     = ws + OFF_EP;
    unsigned short* ZT  = (unsigned short*)(ws + OFF_ZT);
    unsigned short* WbT = (unsigned short*)(ws + OFF_WBT);
    unsigned short* lmb = (unsigned short*)(ws + OFF_LM);

    k_stats   <<<dim3(8, Bb), 384, 0, stream>>>(x, ps);
    k_ctrl    <<<Bb, 384, 0, stream>>>(x, ps, w1, b1, w_rot, b_rot, w_rg, b_rg, w_lg, b_lg,
                                       w_sc, b_sc, sbasis, sstr, rc, rg, lg, scalev, lmb);
    k_prep    <<<200, 256, 0, stream>>>(lb, rb, n2, P, Q, Pb);
    k_gramqw  <<<128, 512, 0, stream>>>(P, Q, Wsh, G, QW);
    k_cayley  <<<Bb, 512, 0, stream>>>(G, rc, n2, rg, Ep);
    k_zmatT   <<<dim3(32, Bb), 384, 0, stream>>>(Ep, QW, ZT);
    k_wbt     <<<dim3(36, Bb), 256, 0, stream>>>(ZT, Pb, Wsh, WbT);
    k_lm      <<<2048, 384, 0, stream>>>(x, kw, lg, lmb);
    k_gemm_nt <<<6528, 256, 0, stream>>>(lmb, WbT, bias, scalev, out);
}